// Round 11
// baseline (1008.730 us; speedup 1.0000x reference)
//
#include <hip/hip_runtime.h>
#include <cstdint>

// ---------------------------------------------------------------------------
// GCN: 3x GCNConv(+ELU) + linear head.
// perm is quarter-major: 4 per-src-quarter CSRs (rpq[q][node]); each agg
// launch walks only its quarter(s) -> per-launch stream = quarter perm
// (12.8MB) and gather slice = 3.2MB (fits 4MB/XCD L2; proven by round-8
// FETCH=30MB). Build uses only proven-cheap write patterns:
//   qcount/qscan4    : per-quarter totals -> aligned region bases
//   split_scatter    : 4-way partition by src-quarter, wave-ballot
//                      compaction (sequential wave streams), fused
//                      (quarter,bucket) 2048-bin histogram
//   bucket_scan2048  : bases for (quarter,bucket) bedge segments
//   bucket_scatter x4: round-5 LDS-staged 512-bin scatter per quarter
//   sort_deg         : deg/dinv + per-(node,quarter) scans -> rpq
//   sort_scatter     : per (q,bucket) block, 256 LDS cursors, contiguous
//                      region writes, norm fused
// A(XW)=(AX)W: gather passes run at F=16,16,32.
// ---------------------------------------------------------------------------

typedef float __attribute__((ext_vector_type(4))) f4v;

__device__ inline int2 ldnt2(const int2* p) {
    long long v = __builtin_nontemporal_load((const long long*)p);
    int2 r;
    r.x = (int)(unsigned)(v & 0xFFFFFFFFLL);
    r.y = (int)(unsigned)((unsigned long long)v >> 32);
    return r;
}
__device__ inline float4 ldnt4(const float4* p) {
    f4v v = __builtin_nontemporal_load((const f4v*)p);
    float4 r;
    r.x = v.x; r.y = v.y; r.z = v.z; r.w = v.w;
    return r;
}

__device__ inline int quarter_of(int s, int qs) {
    return (s >= qs) + (s >= 2 * qs) + (s >= 3 * qs);
}

// ---- P1: per-quarter edge totals (quarter = f(src)).
__global__ void __launch_bounds__(256) qcount(const int* __restrict__ src,
                                              int* __restrict__ qtot,
                                              int E, int qs, int chunk) {
    __shared__ int h[4];
    int t = threadIdx.x;
    if (t < 4) h[t] = 0;
    __syncthreads();
    int c0 = blockIdx.x * chunk;
    int c1 = min(E, c0 + chunk);
    int l0 = 0, l1 = 0, l2 = 0, l3 = 0;
    for (int i = c0 + t; i < c1; i += 256) {
        int q = quarter_of(src[i], qs);
        l0 += (q == 0); l1 += (q == 1); l2 += (q == 2); l3 += (q == 3);
    }
    if (l0) atomicAdd(&h[0], l0);
    if (l1) atomicAdd(&h[1], l1);
    if (l2) atomicAdd(&h[2], l2);
    if (l3) atomicAdd(&h[3], l3);
    __syncthreads();
    if (t < 4 && h[t]) atomicAdd(&qtot[t], h[t]);
}

// ---- P2: quarter region bases (aligned to 4 edges), cursors, lengths.
__global__ void qscan4(const int* __restrict__ qtot, int* __restrict__ qbase,
                       int* __restrict__ qcur, int* __restrict__ qlen) {
    if (threadIdx.x == 0 && blockIdx.x == 0) {
        int base = 0;
        for (int q = 0; q < 4; ++q) {
            qbase[q] = base;
            qcur[q] = base;
            qlen[q] = qtot[q];
            base += (qtot[q] + 3) & ~3;
        }
    }
}

// ---- P3: partition edges into quarter regions (ed=(dst,src), ew=w) with
// wave-ballot compaction; fused (quarter,bucket) histogram.
__global__ void __launch_bounds__(256) split_scatter(const int* __restrict__ src,
                                                     const int* __restrict__ dst,
                                                     const float* __restrict__ w,
                                                     int* __restrict__ qcur,
                                                     int2* __restrict__ ed,
                                                     float* __restrict__ ew,
                                                     int* __restrict__ bcnt,
                                                     int E, int qs) {
    __shared__ int h[2048];
    int t = threadIdx.x;
    int lane = t & 63;
    for (int i = t; i < 2048; i += 256) h[i] = 0;
    __syncthreads();

    int c0 = blockIdx.x * 4096;
    int my_s[16], my_d[16], my_q[16];
    float my_w[16];
#pragma unroll
    for (int k = 0; k < 4; ++k) {
        int e0 = c0 + (t + k * 256) * 4;
        if (e0 + 4 <= E) {
            int4 d4 = *(const int4*)(dst + e0);
            int4 s4 = *(const int4*)(src + e0);
            float4 w4 = *(const float4*)(w + e0);
            my_d[k*4+0]=d4.x; my_d[k*4+1]=d4.y; my_d[k*4+2]=d4.z; my_d[k*4+3]=d4.w;
            my_s[k*4+0]=s4.x; my_s[k*4+1]=s4.y; my_s[k*4+2]=s4.z; my_s[k*4+3]=s4.w;
            my_w[k*4+0]=w4.x; my_w[k*4+1]=w4.y; my_w[k*4+2]=w4.z; my_w[k*4+3]=w4.w;
        } else {
#pragma unroll
            for (int j = 0; j < 4; ++j) {
                int e = e0 + j;
                bool ok = e < E;
                my_d[k*4+j] = ok ? dst[e] : -1;
                my_s[k*4+j] = ok ? src[e] : 0;
                my_w[k*4+j] = ok ? w[e] : 0.f;
            }
        }
    }
#pragma unroll
    for (int j = 0; j < 16; ++j)
        my_q[j] = (my_d[j] >= 0) ? quarter_of(my_s[j], qs) : -1;

    // fused (quarter,bucket) histogram
#pragma unroll
    for (int j = 0; j < 16; ++j)
        if (my_q[j] >= 0)
            atomicAdd(&h[(my_q[j] << 9) | (((unsigned)my_d[j]) >> 8)], 1);

    // wave totals per quarter
    int wt[4] = {0, 0, 0, 0};
#pragma unroll
    for (int j = 0; j < 16; ++j)
        if (my_q[j] >= 0) wt[my_q[j]]++;
#pragma unroll
    for (int q = 0; q < 4; ++q)
        for (int o = 32; o; o >>= 1) wt[q] += __shfl_down(wt[q], o);

    // wave reservation + broadcast
    int wb[4];
#pragma unroll
    for (int q = 0; q < 4; ++q) {
        int v = 0;
        if (lane == 0 && wt[q]) v = atomicAdd(&qcur[q], wt[q]);
        wb[q] = __shfl(v, 0);
    }

    // ballot-compacted sequential writes
    unsigned long long lmask = (1ull << lane) - 1ull;
    int wc0 = wb[0], wc1 = wb[1], wc2 = wb[2], wc3 = wb[3];
#pragma unroll
    for (int j = 0; j < 16; ++j) {
#pragma unroll
        for (int q = 0; q < 4; ++q) {
            unsigned long long m = __ballot(my_q[j] == q);
            int base = (q == 0) ? wc0 : (q == 1) ? wc1 : (q == 2) ? wc2 : wc3;
            if (my_q[j] == q) {
                int pos = base + (int)__popcll(m & lmask);
                ed[pos] = make_int2(my_d[j], my_s[j]);
                ew[pos] = my_w[j];
            }
            int cnt = (int)__popcll(m);
            if (q == 0) wc0 += cnt; else if (q == 1) wc1 += cnt;
            else if (q == 2) wc2 += cnt; else wc3 += cnt;
        }
    }
    __syncthreads();
    for (int i = t; i < 2048; i += 256)
        if (h[i]) atomicAdd(&bcnt[i], h[i]);
}

// ---- P4: scan 2048 (quarter,bucket) bins -> boff[2049], gcur.
__global__ void __launch_bounds__(512) bucket_scan2048(const int* __restrict__ bcnt,
                                                       int* __restrict__ boff,
                                                       int* __restrict__ gcur) {
    __shared__ int part[512];
    int t = threadIdx.x;
    int c[4];
    int s = 0;
#pragma unroll
    for (int j = 0; j < 4; ++j) { c[j] = bcnt[t * 4 + j]; s += c[j]; }
    part[t] = s;
    __syncthreads();
    for (int off = 1; off < 512; off <<= 1) {
        int v = part[t];
        int a = (t >= off) ? part[t - off] : 0;
        __syncthreads();
        part[t] = v + a;
        __syncthreads();
    }
    int run = part[t] - s;
#pragma unroll
    for (int j = 0; j < 4; ++j) {
        boff[t * 4 + j] = run;
        gcur[t * 4 + j] = run;
        run += c[j];
    }
    if (t == 511) boff[2048] = run;
}

// ---- P5: per-quarter LDS-staged 512-bin bucket scatter (round-5 pattern).
// pack: (local_dst(8b) << 24) | src(24b)
__global__ void __launch_bounds__(256) bucket_scatter(const int2* __restrict__ ed,
                                                      const float* __restrict__ ew,
                                                      const int* __restrict__ qbase,
                                                      const int* __restrict__ qlen,
                                                      int* __restrict__ gcur,
                                                      int2* __restrict__ bedge,
                                                      int q) {
    __shared__ int hc[512];     // histogram -> cursor
    __shared__ int gb[512];
    __shared__ int part[256];
    __shared__ int2 sedge[4096];
    __shared__ unsigned short sbuck[4096];

    int ql = qlen[q];
    int toff = blockIdx.x * 4096;
    if (toff >= ql) return;
    int c0 = qbase[q] + toff;
    int mtile = min(4096, ql - toff);
    int t = threadIdx.x;

    for (int i = t; i < 512; i += 256) hc[i] = 0;
    __syncthreads();

    int my_d[16], my_s[16];
    float my_w[16];
    const int4* ed4 = (const int4*)ed;
    const float2* ew2 = (const float2*)ew;
#pragma unroll
    for (int k = 0; k < 8; ++k) {
        int rel = (t + k * 256) * 2;
        int gi = (c0 >> 1) + t + k * 256;
        if (rel + 1 < mtile) {
            int4 v = ed4[gi];
            float2 wv = ew2[gi];
            my_d[2*k] = v.x; my_s[2*k] = v.y;
            my_d[2*k+1] = v.z; my_s[2*k+1] = v.w;
            my_w[2*k] = wv.x; my_w[2*k+1] = wv.y;
        } else {
#pragma unroll
            for (int u = 0; u < 2; ++u) {
                if (rel + u < mtile) {
                    int2 e = ed[c0 + rel + u];
                    my_d[2*k+u] = e.x; my_s[2*k+u] = e.y;
                    my_w[2*k+u] = ew[c0 + rel + u];
                } else {
                    my_d[2*k+u] = -1; my_s[2*k+u] = 0; my_w[2*k+u] = 0.f;
                }
            }
        }
    }
#pragma unroll
    for (int j = 0; j < 16; ++j)
        if (my_d[j] >= 0) atomicAdd(&hc[((unsigned)my_d[j]) >> 8], 1);
    __syncthreads();

    int a0 = hc[2*t], a1 = hc[2*t+1];
    int s = a0 + a1;
    part[t] = s;
    __syncthreads();
    for (int off = 1; off < 256; off <<= 1) {
        int v = part[t];
        int a = (t >= off) ? part[t - off] : 0;
        __syncthreads();
        part[t] = v + a;
        __syncthreads();
    }
    int excl = part[t] - s;
    if (a0) gb[2*t]   = atomicAdd(&gcur[2*t],   a0) - excl;
    if (a1) gb[2*t+1] = atomicAdd(&gcur[2*t+1], a1) - (excl + a0);
    hc[2*t] = excl;
    hc[2*t+1] = excl + a0;
    __syncthreads();

#pragma unroll
    for (int j = 0; j < 16; ++j) {
        int d = my_d[j];
        if (d < 0) continue;
        unsigned ud = (unsigned)d;
        int b = ud >> 8;
        int p = atomicAdd(&hc[b], 1);
        sedge[p] = make_int2((int)(((ud & 255u) << 24) | (unsigned)my_s[j]),
                             __float_as_int(my_w[j]));
        sbuck[p] = (unsigned short)b;
    }
    __syncthreads();

    for (int i = t; i < mtile; i += 256) {
        int b = sbuck[i];
        bedge[gb[b] + i] = sedge[i];
    }
}

// ---- P6: per-bucket deg -> dinv ; per-(node,quarter) scans -> rpq.
__global__ void __launch_bounds__(256) sort_deg(const int* __restrict__ boff,
                                                const int2* __restrict__ bedge,
                                                float* __restrict__ dinv,
                                                int* __restrict__ rpq, int N) {
    __shared__ float deg[256];
    __shared__ int cnt[1024];
    __shared__ int part[256];
    int b = blockIdx.x;
    int t = threadIdx.x;
    deg[t] = 0.f;
    for (int i = t; i < 1024; i += 256) cnt[i] = 0;
    __syncthreads();
    for (int q = 0; q < 4; ++q) {
        int s0 = boff[q * 512 + b], s1 = boff[q * 512 + b + 1];
        for (int i = s0 + t; i < s1; i += 256) {
            int2 e = bedge[i];
            unsigned ux = (unsigned)e.x;
            int l = (int)(ux >> 24);
            atomicAdd(&deg[l], __int_as_float(e.y));
            atomicAdd(&cnt[q * 256 + l], 1);
        }
    }
    __syncthreads();
    int node = b * 256 + t;
    if (node < N) dinv[node] = rsqrtf(deg[t] + 1.0f);
    for (int q = 0; q < 4; ++q) {
        __syncthreads();
        int c = cnt[q * 256 + t];
        part[t] = c;
        __syncthreads();
        for (int off = 1; off < 256; off <<= 1) {
            int v = part[t];
            int a = (t >= off) ? part[t - off] : 0;
            __syncthreads();
            part[t] = v + a;
            __syncthreads();
        }
        int excl = part[t] - c;
        if (node < N) rpq[(size_t)q * (N + 1) + node] = boff[q * 512 + b] + excl;
    }
    if (b == 0 && t < 4)
        rpq[(size_t)t * (N + 1) + N] = boff[t * 512 + gridDim.x];
}

// ---- P7: bedge -> perm (quarter-major CSR order), norm fused.
__global__ void __launch_bounds__(256) sort_scatter(const int* __restrict__ boff,
                                                    const int2* __restrict__ bedge,
                                                    const int* __restrict__ rpq,
                                                    const float* __restrict__ dinv,
                                                    int2* __restrict__ perm, int N) {
    __shared__ int cur[256];
    __shared__ float sdv[256];
    int b = blockIdx.x;
    int q = blockIdx.y;
    int t = threadIdx.x;
    int node = b * 256 + t;
    cur[t] = (node < N) ? rpq[(size_t)q * (N + 1) + node] : 0;
    sdv[t] = (node < N) ? dinv[node] : 0.f;
    __syncthreads();
    int s0 = boff[q * 512 + b], s1 = boff[q * 512 + b + 1];
    for (int i = s0 + t; i < s1; i += 256) {
        int2 e = bedge[i];
        unsigned ux = (unsigned)e.x;
        int l = (int)(ux >> 24);
        int sidx = (int)(ux & 0xFFFFFFu);
        float nm = dinv[sidx] * __int_as_float(e.y) * sdv[l];
        int pos = atomicAdd(&cur[l], 1);
        perm[pos] = make_int2(sidx, __float_as_int(nm));
    }
}

// x[N,256] @ W[256,16] -> xw[N,16].
__global__ void __launch_bounds__(256) gemm_x16(const float* __restrict__ x,
                                                const float* __restrict__ W,
                                                float* __restrict__ xw, int N) {
    __shared__ float Ws[256 * 16];
    for (int i = threadIdx.x; i < 256 * 16; i += 256) Ws[i] = W[i];
    __syncthreads();
    int c = threadIdx.x & 15;
    int rl = threadIdx.x >> 4;
    int r = blockIdx.x * 16 + rl;
    if (r >= N) return;
    const float4* x4 = (const float4*)(x + (size_t)r * 256);
    float acc = 0.f;
#pragma unroll 8
    for (int k4 = 0; k4 < 64; ++k4) {
        float4 v = ldnt4(x4 + k4);
        const float* wr = &Ws[k4 * 64 + c];
        acc += v.x * wr[0] + v.y * wr[16] + v.z * wr[32] + v.w * wr[48];
    }
    xw[(size_t)r * 16 + c] = acc;
}

// in[N,K] @ W[K,F] + bias -> out[N,F], optional ELU on output.
template <int K, int F, bool OUT_ELU>
__global__ void __launch_bounds__(256) gemm_small(const float* __restrict__ in,
                                                  const float* __restrict__ W,
                                                  const float* __restrict__ bias,
                                                  float* __restrict__ out, int N) {
    constexpr int ROWS = 256 / F;
    __shared__ float Ws[K * F];
    __shared__ float Is[ROWS * K];
    for (int i = threadIdx.x; i < K * F; i += 256) Ws[i] = W[i];
    int r0 = blockIdx.x * ROWS;
    for (int i = threadIdx.x; i < ROWS * K; i += 256)
        Is[i] = in[(size_t)r0 * K + i];
    __syncthreads();
    int c = threadIdx.x % F;
    int rl = threadIdx.x / F;
    float acc = bias[c];
#pragma unroll
    for (int k = 0; k < K; ++k) acc += Is[rl * K + k] * Ws[k * F + c];
    if (OUT_ELU) acc = acc > 0.f ? acc : expm1f(acc);
    out[(size_t)(r0 + rl) * F + c] = acc;
}

// ---- Quarter-phased register-accumulator gather-aggregate (round-9 kernel).
// One launch per phase (S quarters). flags: bit0 = init (self-loop [+bias]),
// bit1 = final (apply ELU if template ELU).
template <int F, int S, bool ELU>
__global__ void __launch_bounds__(256) agg_q(const int* __restrict__ rpq,
                                             const int2* __restrict__ perm,
                                             const float* __restrict__ xw,
                                             const float* __restrict__ dinv,
                                             const float* __restrict__ bias,
                                             float* __restrict__ out,
                                             int N, int q0, int flags) {
    constexpr int G = F / 4;
    constexpr int NPB = 256 / G;
    int node = blockIdx.x * NPB + threadIdx.x / G;
    int q = threadIdx.x % G;
    if (node >= N) return;
    const float4* xw4 = (const float4*)xw;
    float4* out4 = (float4*)out;
    float4 a0, a1, a2, a3;
    if (flags & 1) {
        float di = dinv[node];
        float d2 = di * di;
        float4 s = xw4[(size_t)node * G + q];
        a0.x = d2 * s.x; a0.y = d2 * s.y; a0.z = d2 * s.z; a0.w = d2 * s.w;
        if (bias) {
            float4 b4 = ((const float4*)bias)[q];
            a0.x += b4.x; a0.y += b4.y; a0.z += b4.z; a0.w += b4.w;
        }
    } else {
        a0 = out4[(size_t)node * G + q];
    }
    a1 = make_float4(0.f, 0.f, 0.f, 0.f);
    a2 = a1; a3 = a1;
#pragma unroll
    for (int ss = 0; ss < S; ++ss) {
        const int* rp = rpq + (size_t)(q0 + ss) * (N + 1);
        int j = rp[node];
        int je = rp[node + 1];
        for (; j + 3 < je; j += 4) {
            int2 p0 = ldnt2(perm + j);
            int2 p1 = ldnt2(perm + j + 1);
            int2 p2 = ldnt2(perm + j + 2);
            int2 p3 = ldnt2(perm + j + 3);
            float4 v0 = xw4[(size_t)p0.x * G + q];
            float4 v1 = xw4[(size_t)p1.x * G + q];
            float4 v2 = xw4[(size_t)p2.x * G + q];
            float4 v3 = xw4[(size_t)p3.x * G + q];
            float n0 = __int_as_float(p0.y);
            float n1 = __int_as_float(p1.y);
            float n2 = __int_as_float(p2.y);
            float n3 = __int_as_float(p3.y);
            a0.x += n0 * v0.x; a0.y += n0 * v0.y; a0.z += n0 * v0.z; a0.w += n0 * v0.w;
            a1.x += n1 * v1.x; a1.y += n1 * v1.y; a1.z += n1 * v1.z; a1.w += n1 * v1.w;
            a2.x += n2 * v2.x; a2.y += n2 * v2.y; a2.z += n2 * v2.z; a2.w += n2 * v2.w;
            a3.x += n3 * v3.x; a3.y += n3 * v3.y; a3.z += n3 * v3.z; a3.w += n3 * v3.w;
        }
        for (; j < je; ++j) {
            int2 p0 = ldnt2(perm + j);
            float4 v0 = xw4[(size_t)p0.x * G + q];
            float n0 = __int_as_float(p0.y);
            a0.x += n0 * v0.x; a0.y += n0 * v0.y; a0.z += n0 * v0.z; a0.w += n0 * v0.w;
        }
    }
    float4 r;
    r.x = (a0.x + a1.x) + (a2.x + a3.x);
    r.y = (a0.y + a1.y) + (a2.y + a3.y);
    r.z = (a0.z + a1.z) + (a2.z + a3.z);
    r.w = (a0.w + a1.w) + (a2.w + a3.w);
    if (ELU && (flags & 2)) {
        r.x = r.x > 0.f ? r.x : expm1f(r.x);
        r.y = r.y > 0.f ? r.y : expm1f(r.y);
        r.z = r.z > 0.f ? r.z : expm1f(r.z);
        r.w = r.w > 0.f ? r.w : expm1f(r.w);
    }
    out4[(size_t)node * G + q] = r;
}

extern "C" void kernel_launch(void* const* d_in, const int* in_sizes, int n_in,
                              void* d_out, int out_size, void* d_ws, size_t ws_size,
                              hipStream_t stream) {
    const float* x  = (const float*)d_in[0];
    const int*   ei = (const int*)d_in[1];
    const float* w  = (const float*)d_in[2];
    const float* W0 = (const float*)d_in[3];
    const float* b0 = (const float*)d_in[4];
    const float* W1 = (const float*)d_in[5];
    const float* b1 = (const float*)d_in[6];
    const float* W2 = (const float*)d_in[7];
    const float* b2 = (const float*)d_in[8];
    const float* Wm = (const float*)d_in[9];
    const float* bm = (const float*)d_in[10];
    float* out = (float*)d_out;

    const int N = in_sizes[0] / 256;
    const int E = in_sizes[2];
    const int* src = ei;
    const int* dst = ei + E;
    const int nbuck = (N + 255) >> 8;      // 256-node buckets (<=512)
    const int qs = (N + 3) / 4;            // src-quarter size

    char* ws = (char*)d_ws;
    size_t off = 0;
    auto alloc = [&](size_t bytes) {
        void* p = ws + off;
        off = (off + bytes + 255) & ~(size_t)255;
        return p;
    };
    float* dinv  = (float*)alloc((size_t)N * 4);
    int*   rpq   = (int*)alloc((size_t)4 * (N + 1) * 4);
    int*   qtot  = (int*)alloc(64);
    int*   qbase = (int*)alloc(64);
    int*   qcur  = (int*)alloc(64);
    int*   qlen  = (int*)alloc(64);
    int*   bcnt  = (int*)alloc(2056 * 4);
    int*   boff  = (int*)alloc(2056 * 4);
    int*   gcur  = (int*)alloc(2056 * 4);
    // REGION_A: first (ed + ew), later aliased by (perm + BUF_A + BUF_B)
    size_t edA   = (size_t)(E + 16) * 8 + (size_t)E * 4;
    size_t permA = (size_t)E * 8 + 512 + (size_t)N * 256 + 512;
    char*  regA  = (char*)alloc(edA > permA ? edA : permA);
    int2*  bedge = (int2*)alloc((size_t)E * 8);

    int2*  ed    = (int2*)regA;
    float* ew    = (float*)(regA + (size_t)(E + 16) * 8);
    int2*  perm  = (int2*)regA;
    float* BUF_A = (float*)(regA + (((size_t)E * 8 + 511) & ~(size_t)255));
    float* BUF_B = BUF_A + (size_t)N * 32;

    hipMemsetAsync(bcnt, 0, 2048 * 4, stream);
    hipMemsetAsync(qtot, 0, 16, stream);

    const int ebl = (E + 4095) / 4096;

    // ---- build quarter-major CSR (layer-invariant)
    qcount<<<(E + 8191) / 8192, 256, 0, stream>>>(src, qtot, E, qs, 8192);
    qscan4<<<1, 64, 0, stream>>>(qtot, qbase, qcur, qlen);
    split_scatter<<<ebl, 256, 0, stream>>>(src, dst, w, qcur, ed, ew, bcnt, E, qs);
    bucket_scan2048<<<1, 512, 0, stream>>>(bcnt, boff, gcur);
    for (int q = 0; q < 4; ++q)
        bucket_scatter<<<ebl, 256, 0, stream>>>(ed, ew, qbase, qlen, gcur + q * 512, bedge, q);
    sort_deg<<<nbuck, 256, 0, stream>>>(boff, bedge, dinv, rpq, N);
    sort_scatter<<<dim3(nbuck, 4), 256, 0, stream>>>(boff, bedge, rpq, dinv, perm, N);

    const int AGB16 = (N + 63) / 64;
    const int AGB32 = (N + 31) / 32;

    // ---- layer 0: XW = x@W0 ; h1 = elu(A.XW + b0)   [2 phases x 2 quarters]
    gemm_x16<<<(N + 15) / 16, 256, 0, stream>>>(x, W0, BUF_A, N);
    agg_q<16, 2, true><<<AGB16, 256, 0, stream>>>(rpq, perm, BUF_A, dinv, b0, BUF_B, N, 0, 1);
    agg_q<16, 2, true><<<AGB16, 256, 0, stream>>>(rpq, perm, BUF_A, dinv, b0, BUF_B, N, 2, 2);

    // ---- layer 1: AG1 = A.h1 ; h2 = elu(AG1@W1 + b1)
    agg_q<16, 2, false><<<AGB16, 256, 0, stream>>>(rpq, perm, BUF_B, dinv, nullptr, BUF_A, N, 0, 1);
    agg_q<16, 2, false><<<AGB16, 256, 0, stream>>>(rpq, perm, BUF_B, dinv, nullptr, BUF_A, N, 2, 0);
    gemm_small<16, 32, true><<<(N + 7) / 8, 256, 0, stream>>>(BUF_A, W1, b1, BUF_B, N);

    // ---- layer 2: AG2 = A.h2 ; h3 = elu(AG2@W2 + b2)  [4 phases x 1 quarter]
    agg_q<32, 1, false><<<AGB32, 256, 0, stream>>>(rpq, perm, BUF_B, dinv, nullptr, BUF_A, N, 0, 1);
    agg_q<32, 1, false><<<AGB32, 256, 0, stream>>>(rpq, perm, BUF_B, dinv, nullptr, BUF_A, N, 1, 0);
    agg_q<32, 1, false><<<AGB32, 256, 0, stream>>>(rpq, perm, BUF_B, dinv, nullptr, BUF_A, N, 2, 0);
    agg_q<32, 1, false><<<AGB32, 256, 0, stream>>>(rpq, perm, BUF_B, dinv, nullptr, BUF_A, N, 3, 0);
    gemm_small<32, 32, true><<<(N + 7) / 8, 256, 0, stream>>>(BUF_A, W2, b2, BUF_B, N);

    // ---- head: out = h3@Wm + bm
    gemm_small<32, 16, false><<<(N + 15) / 16, 256, 0, stream>>>(BUF_B, Wm, bm, out, N);
}

// Round 12
// 729.141 us; speedup vs baseline: 1.3834x; 1.3834x over previous
//
#include <hip/hip_runtime.h>
#include <hip/hip_fp16.h>
#include <cstdint>

// ---------------------------------------------------------------------------
// GCN: 3x GCNConv(+ELU) + linear head.
// Build = round-5 proven: hist -> scan -> LDS-tile scatter -> sort_deg ->
// sort_scatter (per-node CSR, norm fused). 622us reference.
// NEW: gather tables stored in FP16 so they fit the 4MB per-XCD L2:
//   L0: XW fp16 [N][16] (3.2MB)  -> agg16 -> h1 fp16 [N][16]
//   L1: h1 table (3.2MB)         -> agg16 -> AG1 fp32
//   L2: h2 fp16 column-blocked [2][N][16] (3.2MB/block) -> 2 feature-disjoint
//       agg16 passes -> AG2 fp32 (no RMW: passes write disjoint columns)
// Accumulation in fp32; perm streamed non-temporally. Feature buffers alias
// the dead bedge region to bound workspace.
// ---------------------------------------------------------------------------

typedef float __attribute__((ext_vector_type(4))) f4v;

__device__ inline int2 ldnt2(const int2* p) {
    long long v = __builtin_nontemporal_load((const long long*)p);
    int2 r;
    r.x = (int)(unsigned)(v & 0xFFFFFFFFLL);
    r.y = (int)(unsigned)((unsigned long long)v >> 32);
    return r;
}
__device__ inline float4 ldnt4(const float4* p) {
    f4v v = __builtin_nontemporal_load((const f4v*)p);
    float4 r;
    r.x = v.x; r.y = v.y; r.z = v.z; r.w = v.w;
    return r;
}

union H2I { __half2 h; int i; };
__device__ inline int h2i(__half2 h) { H2I u; u.h = h; return u.i; }

__device__ inline void acc8(float* a, int4 v, float n) {
    H2I u0, u1, u2, u3;
    u0.i = v.x; u1.i = v.y; u2.i = v.z; u3.i = v.w;
    float2 f0 = __half22float2(u0.h);
    float2 f1 = __half22float2(u1.h);
    float2 f2 = __half22float2(u2.h);
    float2 f3 = __half22float2(u3.h);
    a[0] = fmaf(n, f0.x, a[0]); a[1] = fmaf(n, f0.y, a[1]);
    a[2] = fmaf(n, f1.x, a[2]); a[3] = fmaf(n, f1.y, a[3]);
    a[4] = fmaf(n, f2.x, a[4]); a[5] = fmaf(n, f2.y, a[5]);
    a[6] = fmaf(n, f3.x, a[6]); a[7] = fmaf(n, f3.y, a[7]);
}

__device__ inline int4 pack8h(const float* a) {
    int4 r;
    r.x = h2i(__floats2half2_rn(a[0], a[1]));
    r.y = h2i(__floats2half2_rn(a[2], a[3]));
    r.z = h2i(__floats2half2_rn(a[4], a[5]));
    r.w = h2i(__floats2half2_rn(a[6], a[7]));
    return r;
}

// ---- Pass A: per-bucket edge counts. bucket = dst >> 8.
__global__ void __launch_bounds__(256) bucket_hist(const int* __restrict__ dst,
                                                   int* __restrict__ bcnt,
                                                   int E, int nbuck, int chunk) {
    __shared__ int h[512];
    for (int i = threadIdx.x; i < 512; i += 256) h[i] = 0;
    __syncthreads();
    int c0 = blockIdx.x * chunk;
    int c1 = min(E, c0 + chunk);
    for (int i = c0 + threadIdx.x; i < c1; i += 256)
        atomicAdd(&h[((unsigned)dst[i]) >> 8], 1);
    __syncthreads();
    for (int i = threadIdx.x; i < nbuck; i += 256)
        if (h[i]) atomicAdd(&bcnt[i], h[i]);
}

// ---- scan of bucket counts -> boff[nbuck+1], global cursors.
__global__ void __launch_bounds__(512) bucket_scan(const int* __restrict__ bcnt,
                                                   int* __restrict__ boff,
                                                   int* __restrict__ gcur,
                                                   int nbuck) {
    __shared__ int part[512];
    int t = threadIdx.x;
    part[t] = (t < nbuck) ? bcnt[t] : 0;
    __syncthreads();
    for (int off = 1; off < 512; off <<= 1) {
        int v = part[t];
        int a = (t >= off) ? part[t - off] : 0;
        __syncthreads();
        part[t] = v + a;
        __syncthreads();
    }
    if (t < nbuck) {
        int excl = (t > 0) ? part[t - 1] : 0;
        boff[t] = excl;
        gcur[t] = excl;
        if (t == nbuck - 1) boff[nbuck] = part[t];  // == E
    }
}

// ---- Pass C: LDS-reorder scatter. TILE=4096 edges/block.
__global__ void __launch_bounds__(256) bucket_scatter(const int* __restrict__ src,
                                                      const int* __restrict__ dst,
                                                      const float* __restrict__ w,
                                                      int* __restrict__ gcur,
                                                      int2* __restrict__ bedge,
                                                      int E) {
    constexpr int TILE = 4096;
    __shared__ int h[512];
    __shared__ int lcnt[512];
    __shared__ int lofs[512];
    __shared__ int gb[512];
    __shared__ int part[256];
    __shared__ int2 sedge[TILE];
    __shared__ unsigned short sbuck[TILE];

    int t = threadIdx.x;
    int c0 = blockIdx.x * TILE;
    int mtile = min(TILE, E - c0);

    for (int i = t; i < 512; i += 256) { h[i] = 0; lcnt[i] = 0; }
    __syncthreads();

    int  my_dst[16];
    int  my_src[16];
    float my_w[16];
#pragma unroll
    for (int k = 0; k < 4; ++k) {
        int e0 = c0 + (t + k * 256) * 4;
        if (e0 + 4 <= E) {
            int4 d4 = *(const int4*)(dst + e0);
            int4 s4 = *(const int4*)(src + e0);
            float4 w4 = *(const float4*)(w + e0);
            my_dst[k*4+0]=d4.x; my_dst[k*4+1]=d4.y; my_dst[k*4+2]=d4.z; my_dst[k*4+3]=d4.w;
            my_src[k*4+0]=s4.x; my_src[k*4+1]=s4.y; my_src[k*4+2]=s4.z; my_src[k*4+3]=s4.w;
            my_w[k*4+0]=w4.x;  my_w[k*4+1]=w4.y;  my_w[k*4+2]=w4.z;  my_w[k*4+3]=w4.w;
        } else {
#pragma unroll
            for (int j = 0; j < 4; ++j) {
                int e = e0 + j;
                bool ok = e < E;
                my_dst[k*4+j] = ok ? dst[e] : -1;
                my_src[k*4+j] = ok ? src[e] : 0;
                my_w[k*4+j]   = ok ? w[e] : 0.f;
            }
        }
    }
#pragma unroll
    for (int j = 0; j < 16; ++j)
        if (my_dst[j] >= 0) atomicAdd(&h[((unsigned)my_dst[j]) >> 8], 1);
    __syncthreads();

    int a0 = h[2 * t], a1 = h[2 * t + 1];
    int s = a0 + a1;
    part[t] = s;
    __syncthreads();
    for (int off = 1; off < 256; off <<= 1) {
        int v = part[t];
        int a = (t >= off) ? part[t - off] : 0;
        __syncthreads();
        part[t] = v + a;
        __syncthreads();
    }
    int excl = part[t] - s;
    lofs[2 * t] = excl;
    lofs[2 * t + 1] = excl + a0;
    if (a0) gb[2 * t] = atomicAdd(&gcur[2 * t], a0) - excl;
    if (a1) gb[2 * t + 1] = atomicAdd(&gcur[2 * t + 1], a1) - (excl + a0);
    __syncthreads();

#pragma unroll
    for (int j = 0; j < 16; ++j) {
        int d = my_dst[j];
        if (d < 0) continue;
        unsigned ud = (unsigned)d;
        int b = ud >> 8;
        int p = lofs[b] + atomicAdd(&lcnt[b], 1);
        int2 e;
        e.x = (int)(((ud & 255u) << 24) | (unsigned)my_src[j]);
        e.y = __float_as_int(my_w[j]);
        sedge[p] = e;
        sbuck[p] = (unsigned short)b;
    }
    __syncthreads();

    for (int i = t; i < mtile; i += 256) {
        int b = sbuck[i];
        bedge[gb[b] + i] = sedge[i];
    }
}

// ---- Pass D: per-bucket deg -> row_ptr, dinv.
__global__ void __launch_bounds__(256) sort_deg(const int* __restrict__ boff,
                                                const int2* __restrict__ bedge,
                                                int* __restrict__ row_ptr,
                                                float* __restrict__ dinv,
                                                int N, int E) {
    __shared__ int cnt[256];
    __shared__ float deg[256];
    __shared__ int part[256];
    int b = blockIdx.x;
    int base = boff[b];
    int m = boff[b + 1] - base;
    int t = threadIdx.x;
    cnt[t] = 0;
    deg[t] = 0.f;
    __syncthreads();
    for (int i = t; i < m; i += 256) {
        int2 e = bedge[base + i];
        unsigned l = ((unsigned)e.x) >> 24;
        atomicAdd(&cnt[l], 1);
        atomicAdd(&deg[l], __int_as_float(e.y));
    }
    __syncthreads();
    part[t] = cnt[t];
    __syncthreads();
    for (int off = 1; off < 256; off <<= 1) {
        int v = part[t];
        int a = (t >= off) ? part[t - off] : 0;
        __syncthreads();
        part[t] = v + a;
        __syncthreads();
    }
    int excl = part[t] - cnt[t];
    int node = b * 256 + t;
    if (node < N) {
        row_ptr[node] = base + excl;
        dinv[node] = rsqrtf(deg[t] + 1.0f);
    }
    if (b == 0 && t == 0) row_ptr[N] = E;
}

// ---- Pass E: bedge -> perm (CSR order) with fused norm.
__global__ void __launch_bounds__(256) sort_scatter(const int* __restrict__ boff,
                                                    const int2* __restrict__ bedge,
                                                    const int* __restrict__ row_ptr,
                                                    const float* __restrict__ dinv,
                                                    int2* __restrict__ perm, int N) {
    __shared__ int cur[256];
    __shared__ float sdinv[256];
    int b = blockIdx.x;
    int base = boff[b];
    int m = boff[b + 1] - base;
    int t = threadIdx.x;
    int node = b * 256 + t;
    cur[t] = (node < N) ? row_ptr[node] : 0;
    sdinv[t] = (node < N) ? dinv[node] : 0.f;
    __syncthreads();
    for (int i = t; i < m; i += 256) {
        int2 e = bedge[base + i];
        unsigned ux = (unsigned)e.x;
        unsigned l = ux >> 24;
        int sidx = (int)(ux & 0xFFFFFFu);
        float nm = dinv[sidx] * __int_as_float(e.y) * sdinv[l];
        int pos = atomicAdd(&cur[l], 1);
        int2 p;
        p.x = sidx;
        p.y = __float_as_int(nm);
        perm[pos] = p;
    }
}

// x[N,256] @ W[256,16] -> xw fp16 [N,16].
__global__ void __launch_bounds__(256) gemm_x16(const float* __restrict__ x,
                                                const float* __restrict__ W,
                                                __half* __restrict__ xwh, int N) {
    __shared__ float Ws[256 * 16];
    for (int i = threadIdx.x; i < 256 * 16; i += 256) Ws[i] = W[i];
    __syncthreads();
    int c = threadIdx.x & 15;
    int rl = threadIdx.x >> 4;
    int r = blockIdx.x * 16 + rl;
    if (r >= N) return;
    const float4* x4 = (const float4*)(x + (size_t)r * 256);
    float acc = 0.f;
#pragma unroll 8
    for (int k4 = 0; k4 < 64; ++k4) {
        float4 v = ldnt4(x4 + k4);
        const float* wr = &Ws[k4 * 64 + c];
        acc += v.x * wr[0] + v.y * wr[16] + v.z * wr[32] + v.w * wr[48];
    }
    xwh[(size_t)r * 16 + c] = __float2half_rn(acc);
}

// in[N,K] @ W[K,F] + bias -> out[N,F]. OUT_ELU: apply ELU.
// HALF_CB: write fp16 column-blocked [F/16][N][16]; else fp32 row-major.
template <int K, int F, bool OUT_ELU, bool HALF_CB>
__global__ void __launch_bounds__(256) gemm_small(const float* __restrict__ in,
                                                  const float* __restrict__ W,
                                                  const float* __restrict__ bias,
                                                  void* __restrict__ outv, int N) {
    constexpr int ROWS = 256 / F;
    __shared__ float Ws[K * F];
    __shared__ float Is[ROWS * K];
    for (int i = threadIdx.x; i < K * F; i += 256) Ws[i] = W[i];
    int r0 = blockIdx.x * ROWS;
    for (int i = threadIdx.x; i < ROWS * K; i += 256)
        Is[i] = in[(size_t)r0 * K + i];
    __syncthreads();
    int c = threadIdx.x % F;
    int rl = threadIdx.x / F;
    int r = r0 + rl;
    float acc = bias[c];
#pragma unroll
    for (int k = 0; k < K; ++k) acc += Is[rl * K + k] * Ws[k * F + c];
    if (OUT_ELU) acc = acc > 0.f ? acc : expm1f(acc);
    if (HALF_CB) {
        __half* o = (__half*)outv;
        o[((size_t)(c >> 4) * N + r) * 16 + (c & 15)] = __float2half_rn(acc);
    } else {
        ((float*)outv)[(size_t)r * F + c] = acc;
    }
}

// ---- fp16-table gather-aggregate over a 16-feature block.
// tab: fp16 rows of 16 (int4 index = node*2 + q), q = lane&1 owns 8 features.
// HALF_OUT: out = fp16 [N][16] with bias+ELU fused (layer-0 h1).
// else: out = fp32, float4 index = node*OS + CO + q*2 (OS=4: [N][16];
//       OS=8,CO=0/4: disjoint halves of [N][32]).
template <bool HALF_OUT>
__global__ void __launch_bounds__(256) agg16(const int* __restrict__ row_ptr,
                                             const int2* __restrict__ perm,
                                             const int4* __restrict__ tab,
                                             const float* __restrict__ dinv,
                                             const float* __restrict__ bias,
                                             void* __restrict__ outv,
                                             int N, int OS, int CO) {
    int node = blockIdx.x * 128 + (threadIdx.x >> 1);
    int q = threadIdx.x & 1;
    if (node >= N) return;
    float a0[8], a1[8], a2[8], a3[8];
    {
        float di = dinv[node];
        float d2 = di * di;
#pragma unroll
        for (int i = 0; i < 8; ++i) { a0[i] = 0.f; a1[i] = 0.f; a2[i] = 0.f; a3[i] = 0.f; }
        acc8(a0, tab[(size_t)node * 2 + q], d2);   // self-loop
    }
    int j = row_ptr[node];
    int je = row_ptr[node + 1];
    for (; j + 3 < je; j += 4) {
        int2 p0 = ldnt2(perm + j);
        int2 p1 = ldnt2(perm + j + 1);
        int2 p2 = ldnt2(perm + j + 2);
        int2 p3 = ldnt2(perm + j + 3);
        int4 v0 = tab[(size_t)p0.x * 2 + q];
        int4 v1 = tab[(size_t)p1.x * 2 + q];
        int4 v2 = tab[(size_t)p2.x * 2 + q];
        int4 v3 = tab[(size_t)p3.x * 2 + q];
        acc8(a0, v0, __int_as_float(p0.y));
        acc8(a1, v1, __int_as_float(p1.y));
        acc8(a2, v2, __int_as_float(p2.y));
        acc8(a3, v3, __int_as_float(p3.y));
    }
    for (; j < je; ++j) {
        int2 p0 = ldnt2(perm + j);
        acc8(a0, tab[(size_t)p0.x * 2 + q], __int_as_float(p0.y));
    }
    float r[8];
#pragma unroll
    for (int i = 0; i < 8; ++i) r[i] = (a0[i] + a1[i]) + (a2[i] + a3[i]);
    if (HALF_OUT) {
#pragma unroll
        for (int i = 0; i < 8; ++i) {
            float v = r[i] + bias[q * 8 + i];
            r[i] = v > 0.f ? v : expm1f(v);
        }
        ((int4*)outv)[(size_t)node * 2 + q] = pack8h(r);
    } else {
        float4* o4 = (float4*)outv;
        float4 lo = {r[0], r[1], r[2], r[3]};
        float4 hi = {r[4], r[5], r[6], r[7]};
        size_t base = (size_t)node * OS + CO + q * 2;
        o4[base] = lo;
        o4[base + 1] = hi;
    }
}

extern "C" void kernel_launch(void* const* d_in, const int* in_sizes, int n_in,
                              void* d_out, int out_size, void* d_ws, size_t ws_size,
                              hipStream_t stream) {
    const float* x  = (const float*)d_in[0];
    const int*   ei = (const int*)d_in[1];
    const float* w  = (const float*)d_in[2];
    const float* W0 = (const float*)d_in[3];
    const float* b0 = (const float*)d_in[4];
    const float* W1 = (const float*)d_in[5];
    const float* b1 = (const float*)d_in[6];
    const float* W2 = (const float*)d_in[7];
    const float* b2 = (const float*)d_in[8];
    const float* Wm = (const float*)d_in[9];
    const float* bm = (const float*)d_in[10];
    float* out = (float*)d_out;

    const int N = in_sizes[0] / 256;
    const int E = in_sizes[2];
    const int* src = ei;
    const int* dst = ei + E;
    const int nbuck = (N + 255) >> 8;

    char* ws = (char*)d_ws;
    size_t off = 0;
    auto alloc = [&](size_t bytes) {
        void* p = ws + off;
        off = (off + bytes + 255) & ~(size_t)255;
        return p;
    };
    float* dinv    = (float*)alloc((size_t)N * 4);
    int*   row_ptr = (int*)alloc(((size_t)N + 1) * 4);
    int*   bcnt    = (int*)alloc(520 * 4);
    int*   boff    = (int*)alloc(520 * 4);
    int*   gcur    = (int*)alloc(520 * 4);
    // bedge region (E*8 bytes), aliased by feature buffers after CSR build:
    char*  regE    = (char*)alloc((size_t)E * 8);
    int2*  perm    = (int2*)alloc((size_t)E * 8);

    int2*  bedge = (int2*)regE;
    size_t eo = 0;
    auto sub = [&](size_t bytes) {
        char* p = regE + eo;
        eo = (eo + bytes + 255) & ~(size_t)255;
        return p;
    };
    __half* XW_h  = (__half*)sub((size_t)N * 16 * 2);   // 3.2MB
    __half* H1_h  = (__half*)sub((size_t)N * 16 * 2);   // 3.2MB
    __half* H2_h  = (__half*)sub((size_t)N * 32 * 2);   // 6.4MB col-blocked [2][N][16]
    float*  AG1_f = (float*)sub((size_t)N * 16 * 4);    // 6.4MB
    float*  AG2_f = (float*)sub((size_t)N * 32 * 4);    // 12.8MB
    float*  H3_f  = (float*)sub((size_t)N * 32 * 4);    // 12.8MB  (total ~44.8MB <= E*8)

    hipMemsetAsync(bcnt, 0, 520 * 4, stream);

    const int CH = 8192;
    const int sblk = (E + CH - 1) / CH;

    // ---- build CSR (layer-invariant, round-5 structure)
    bucket_hist<<<sblk, 256, 0, stream>>>(dst, bcnt, E, nbuck, CH);
    bucket_scan<<<1, 512, 0, stream>>>(bcnt, boff, gcur, nbuck);
    bucket_scatter<<<(E + 4095) / 4096, 256, 0, stream>>>(src, dst, w, gcur, bedge, E);
    sort_deg<<<nbuck, 256, 0, stream>>>(boff, bedge, row_ptr, dinv, N, E);
    sort_scatter<<<nbuck, 256, 0, stream>>>(boff, bedge, row_ptr, dinv, perm, N);
    // bedge dead from here; regE reused for feature buffers.

    const int AGB = (N + 127) / 128;

    // ---- layer 0: XW = x@W0 (fp16) ; h1 = elu(A.XW + b0) (fp16)
    gemm_x16<<<(N + 15) / 16, 256, 0, stream>>>(x, W0, XW_h, N);
    agg16<true><<<AGB, 256, 0, stream>>>(row_ptr, perm, (const int4*)XW_h, dinv, b0, H1_h, N, 0, 0);

    // ---- layer 1: AG1 = A.h1 (fp32) ; h2 = elu(AG1@W1 + b1) (fp16 col-block)
    agg16<false><<<AGB, 256, 0, stream>>>(row_ptr, perm, (const int4*)H1_h, dinv, nullptr, AG1_f, N, 4, 0);
    gemm_small<16, 32, true, true><<<(N + 7) / 8, 256, 0, stream>>>(AG1_f, W1, b1, H2_h, N);

    // ---- layer 2: AG2 = A.h2 — two feature-disjoint passes over 3.2MB blocks
    agg16<false><<<AGB, 256, 0, stream>>>(row_ptr, perm, (const int4*)H2_h, dinv, nullptr, AG2_f, N, 8, 0);
    agg16<false><<<AGB, 256, 0, stream>>>(row_ptr, perm, (const int4*)(H2_h + (size_t)N * 16), dinv, nullptr, AG2_f, N, 8, 4);
    gemm_small<32, 32, true, false><<<(N + 7) / 8, 256, 0, stream>>>(AG2_f, W2, b2, H3_f, N);

    // ---- head: out = h3@Wm + bm
    gemm_small<32, 16, false, false><<<(N + 15) / 16, 256, 0, stream>>>(H3_f, Wm, bm, out, N);
}

// Round 13
// 607.909 us; speedup vs baseline: 1.6593x; 1.1994x over previous
//
#include <hip/hip_runtime.h>
#include <hip/hip_fp16.h>
#include <cstdint>

// ---------------------------------------------------------------------------
// GCN: 3x GCNConv(+ELU) + linear head.
// Build = round-5 proven: hist -> scan -> LDS-tile scatter -> sort_deg ->
// sort_scatter (per-node CSR, norm fused).
// Gather tables in FP16 (fit/nearly fit 4MB per-XCD L2):
//   L0: XW fp16 [N][16] (3.2MB) -> agg_es<2> -> h1 fp16 [N][16]
//   L1: h1 (3.2MB)              -> agg_es<2> -> AG1 fp32 [N][16]
//   L2: h2 fp16 [N][32] (6.4MB) -> agg_es<4> -> AG2 fp32 [N][32]
// agg_es: FH feature lanes x 2 edge-half lanes per node (shfl_xor reduce)
// -> 76-100% occupancy (round-12 lesson: 2 lanes/node = 24% occ, latency-
// bound at unchanged FETCH). fp32 accumulation throughout.
// ---------------------------------------------------------------------------

typedef float __attribute__((ext_vector_type(4))) f4v;

__device__ inline int2 ldnt2(const int2* p) {
    long long v = __builtin_nontemporal_load((const long long*)p);
    int2 r;
    r.x = (int)(unsigned)(v & 0xFFFFFFFFLL);
    r.y = (int)(unsigned)((unsigned long long)v >> 32);
    return r;
}
__device__ inline float4 ldnt4(const float4* p) {
    f4v v = __builtin_nontemporal_load((const f4v*)p);
    float4 r;
    r.x = v.x; r.y = v.y; r.z = v.z; r.w = v.w;
    return r;
}

union H2I { __half2 h; int i; };
__device__ inline int h2i(__half2 h) { H2I u; u.h = h; return u.i; }

__device__ inline void acc8(float* a, int4 v, float n) {
    H2I u0, u1, u2, u3;
    u0.i = v.x; u1.i = v.y; u2.i = v.z; u3.i = v.w;
    float2 f0 = __half22float2(u0.h);
    float2 f1 = __half22float2(u1.h);
    float2 f2 = __half22float2(u2.h);
    float2 f3 = __half22float2(u3.h);
    a[0] = fmaf(n, f0.x, a[0]); a[1] = fmaf(n, f0.y, a[1]);
    a[2] = fmaf(n, f1.x, a[2]); a[3] = fmaf(n, f1.y, a[3]);
    a[4] = fmaf(n, f2.x, a[4]); a[5] = fmaf(n, f2.y, a[5]);
    a[6] = fmaf(n, f3.x, a[6]); a[7] = fmaf(n, f3.y, a[7]);
}

__device__ inline int4 pack8h(const float* a) {
    int4 r;
    r.x = h2i(__floats2half2_rn(a[0], a[1]));
    r.y = h2i(__floats2half2_rn(a[2], a[3]));
    r.z = h2i(__floats2half2_rn(a[4], a[5]));
    r.w = h2i(__floats2half2_rn(a[6], a[7]));
    return r;
}

// ---- Pass A: per-bucket edge counts. bucket = dst >> 8.
__global__ void __launch_bounds__(256) bucket_hist(const int* __restrict__ dst,
                                                   int* __restrict__ bcnt,
                                                   int E, int nbuck, int chunk) {
    __shared__ int h[512];
    for (int i = threadIdx.x; i < 512; i += 256) h[i] = 0;
    __syncthreads();
    int c0 = blockIdx.x * chunk;
    int c1 = min(E, c0 + chunk);
    for (int i = c0 + threadIdx.x; i < c1; i += 256)
        atomicAdd(&h[((unsigned)dst[i]) >> 8], 1);
    __syncthreads();
    for (int i = threadIdx.x; i < nbuck; i += 256)
        if (h[i]) atomicAdd(&bcnt[i], h[i]);
}

// ---- scan of bucket counts -> boff[nbuck+1], global cursors.
__global__ void __launch_bounds__(512) bucket_scan(const int* __restrict__ bcnt,
                                                   int* __restrict__ boff,
                                                   int* __restrict__ gcur,
                                                   int nbuck) {
    __shared__ int part[512];
    int t = threadIdx.x;
    part[t] = (t < nbuck) ? bcnt[t] : 0;
    __syncthreads();
    for (int off = 1; off < 512; off <<= 1) {
        int v = part[t];
        int a = (t >= off) ? part[t - off] : 0;
        __syncthreads();
        part[t] = v + a;
        __syncthreads();
    }
    if (t < nbuck) {
        int excl = (t > 0) ? part[t - 1] : 0;
        boff[t] = excl;
        gcur[t] = excl;
        if (t == nbuck - 1) boff[nbuck] = part[t];  // == E
    }
}

// ---- Pass C: LDS-reorder scatter. TILE=4096 edges/block.
__global__ void __launch_bounds__(256) bucket_scatter(const int* __restrict__ src,
                                                      const int* __restrict__ dst,
                                                      const float* __restrict__ w,
                                                      int* __restrict__ gcur,
                                                      int2* __restrict__ bedge,
                                                      int E) {
    constexpr int TILE = 4096;
    __shared__ int h[512];
    __shared__ int lcnt[512];
    __shared__ int lofs[512];
    __shared__ int gb[512];
    __shared__ int part[256];
    __shared__ int2 sedge[TILE];
    __shared__ unsigned short sbuck[TILE];

    int t = threadIdx.x;
    int c0 = blockIdx.x * TILE;
    int mtile = min(TILE, E - c0);

    for (int i = t; i < 512; i += 256) { h[i] = 0; lcnt[i] = 0; }
    __syncthreads();

    int  my_dst[16];
    int  my_src[16];
    float my_w[16];
#pragma unroll
    for (int k = 0; k < 4; ++k) {
        int e0 = c0 + (t + k * 256) * 4;
        if (e0 + 4 <= E) {
            int4 d4 = *(const int4*)(dst + e0);
            int4 s4 = *(const int4*)(src + e0);
            float4 w4 = *(const float4*)(w + e0);
            my_dst[k*4+0]=d4.x; my_dst[k*4+1]=d4.y; my_dst[k*4+2]=d4.z; my_dst[k*4+3]=d4.w;
            my_src[k*4+0]=s4.x; my_src[k*4+1]=s4.y; my_src[k*4+2]=s4.z; my_src[k*4+3]=s4.w;
            my_w[k*4+0]=w4.x;  my_w[k*4+1]=w4.y;  my_w[k*4+2]=w4.z;  my_w[k*4+3]=w4.w;
        } else {
#pragma unroll
            for (int j = 0; j < 4; ++j) {
                int e = e0 + j;
                bool ok = e < E;
                my_dst[k*4+j] = ok ? dst[e] : -1;
                my_src[k*4+j] = ok ? src[e] : 0;
                my_w[k*4+j]   = ok ? w[e] : 0.f;
            }
        }
    }
#pragma unroll
    for (int j = 0; j < 16; ++j)
        if (my_dst[j] >= 0) atomicAdd(&h[((unsigned)my_dst[j]) >> 8], 1);
    __syncthreads();

    int a0 = h[2 * t], a1 = h[2 * t + 1];
    int s = a0 + a1;
    part[t] = s;
    __syncthreads();
    for (int off = 1; off < 256; off <<= 1) {
        int v = part[t];
        int a = (t >= off) ? part[t - off] : 0;
        __syncthreads();
        part[t] = v + a;
        __syncthreads();
    }
    int excl = part[t] - s;
    lofs[2 * t] = excl;
    lofs[2 * t + 1] = excl + a0;
    if (a0) gb[2 * t] = atomicAdd(&gcur[2 * t], a0) - excl;
    if (a1) gb[2 * t + 1] = atomicAdd(&gcur[2 * t + 1], a1) - (excl + a0);
    __syncthreads();

#pragma unroll
    for (int j = 0; j < 16; ++j) {
        int d = my_dst[j];
        if (d < 0) continue;
        unsigned ud = (unsigned)d;
        int b = ud >> 8;
        int p = lofs[b] + atomicAdd(&lcnt[b], 1);
        int2 e;
        e.x = (int)(((ud & 255u) << 24) | (unsigned)my_src[j]);
        e.y = __float_as_int(my_w[j]);
        sedge[p] = e;
        sbuck[p] = (unsigned short)b;
    }
    __syncthreads();

    for (int i = t; i < mtile; i += 256) {
        int b = sbuck[i];
        bedge[gb[b] + i] = sedge[i];
    }
}

// ---- Pass D: per-bucket deg -> row_ptr, dinv.
__global__ void __launch_bounds__(256) sort_deg(const int* __restrict__ boff,
                                                const int2* __restrict__ bedge,
                                                int* __restrict__ row_ptr,
                                                float* __restrict__ dinv,
                                                int N, int E) {
    __shared__ int cnt[256];
    __shared__ float deg[256];
    __shared__ int part[256];
    int b = blockIdx.x;
    int base = boff[b];
    int m = boff[b + 1] - base;
    int t = threadIdx.x;
    cnt[t] = 0;
    deg[t] = 0.f;
    __syncthreads();
    for (int i = t; i < m; i += 256) {
        int2 e = bedge[base + i];
        unsigned l = ((unsigned)e.x) >> 24;
        atomicAdd(&cnt[l], 1);
        atomicAdd(&deg[l], __int_as_float(e.y));
    }
    __syncthreads();
    part[t] = cnt[t];
    __syncthreads();
    for (int off = 1; off < 256; off <<= 1) {
        int v = part[t];
        int a = (t >= off) ? part[t - off] : 0;
        __syncthreads();
        part[t] = v + a;
        __syncthreads();
    }
    int excl = part[t] - cnt[t];
    int node = b * 256 + t;
    if (node < N) {
        row_ptr[node] = base + excl;
        dinv[node] = rsqrtf(deg[t] + 1.0f);
    }
    if (b == 0 && t == 0) row_ptr[N] = E;
}

// ---- Pass E: bedge -> perm (CSR order) with fused norm.
__global__ void __launch_bounds__(256) sort_scatter(const int* __restrict__ boff,
                                                    const int2* __restrict__ bedge,
                                                    const int* __restrict__ row_ptr,
                                                    const float* __restrict__ dinv,
                                                    int2* __restrict__ perm, int N) {
    __shared__ int cur[256];
    __shared__ float sdinv[256];
    int b = blockIdx.x;
    int base = boff[b];
    int m = boff[b + 1] - base;
    int t = threadIdx.x;
    int node = b * 256 + t;
    cur[t] = (node < N) ? row_ptr[node] : 0;
    sdinv[t] = (node < N) ? dinv[node] : 0.f;
    __syncthreads();
    for (int i = t; i < m; i += 256) {
        int2 e = bedge[base + i];
        unsigned ux = (unsigned)e.x;
        unsigned l = ux >> 24;
        int sidx = (int)(ux & 0xFFFFFFu);
        float nm = dinv[sidx] * __int_as_float(e.y) * sdinv[l];
        int pos = atomicAdd(&cur[l], 1);
        int2 p;
        p.x = sidx;
        p.y = __float_as_int(nm);
        perm[pos] = p;
    }
}

// x[N,256] @ W[256,16] -> xw fp16 [N,16].
__global__ void __launch_bounds__(256) gemm_x16(const float* __restrict__ x,
                                                const float* __restrict__ W,
                                                __half* __restrict__ xwh, int N) {
    __shared__ float Ws[256 * 16];
    for (int i = threadIdx.x; i < 256 * 16; i += 256) Ws[i] = W[i];
    __syncthreads();
    int c = threadIdx.x & 15;
    int rl = threadIdx.x >> 4;
    int r = blockIdx.x * 16 + rl;
    if (r >= N) return;
    const float4* x4 = (const float4*)(x + (size_t)r * 256);
    float acc = 0.f;
#pragma unroll 8
    for (int k4 = 0; k4 < 64; ++k4) {
        float4 v = ldnt4(x4 + k4);
        const float* wr = &Ws[k4 * 64 + c];
        acc += v.x * wr[0] + v.y * wr[16] + v.z * wr[32] + v.w * wr[48];
    }
    xwh[(size_t)r * 16 + c] = __float2half_rn(acc);
}

// in[N,K] @ W[K,F] + bias -> out[N,F]. OUT_ELU: apply ELU.
// HALF_ROW: write fp16 row-major [N][F]; else fp32 row-major.
template <int K, int F, bool OUT_ELU, bool HALF_ROW>
__global__ void __launch_bounds__(256) gemm_small(const float* __restrict__ in,
                                                  const float* __restrict__ W,
                                                  const float* __restrict__ bias,
                                                  void* __restrict__ outv, int N) {
    constexpr int ROWS = 256 / F;
    __shared__ float Ws[K * F];
    __shared__ float Is[ROWS * K];
    for (int i = threadIdx.x; i < K * F; i += 256) Ws[i] = W[i];
    int r0 = blockIdx.x * ROWS;
    for (int i = threadIdx.x; i < ROWS * K; i += 256)
        Is[i] = in[(size_t)r0 * K + i];
    __syncthreads();
    int c = threadIdx.x % F;
    int rl = threadIdx.x / F;
    int r = r0 + rl;
    float acc = bias[c];
#pragma unroll
    for (int k = 0; k < K; ++k) acc += Is[rl * K + k] * Ws[k * F + c];
    if (OUT_ELU) acc = acc > 0.f ? acc : expm1f(acc);
    if (HALF_ROW) {
        ((__half*)outv)[(size_t)r * F + c] = __float2half_rn(acc);
    } else {
        ((float*)outv)[(size_t)r * F + c] = acc;
    }
}

// ---- fp16-table gather-aggregate with edge-split lanes.
// Table: fp16 row-major [N][8*FH] (int4 chunk index = node*FH + q).
// Lanes per node = FH*2: q = sub%FH (feature chunk), e = sub/FH (edge half).
// Edge-pair reduced via shfl_xor(FH); lane e==0 writes.
// HALF_OUT: out fp16 [N][8*FH] with bias+ELU fused. Else fp32 [N][8*FH].
template <int FH, bool HALF_OUT>
__global__ void __launch_bounds__(256) agg_es(const int* __restrict__ row_ptr,
                                              const int2* __restrict__ perm,
                                              const int4* __restrict__ tab,
                                              const float* __restrict__ dinv,
                                              const float* __restrict__ bias,
                                              void* __restrict__ outv, int N) {
    constexpr int LPN = FH * 2;
    constexpr int NPB = 256 / LPN;
    int node = blockIdx.x * NPB + threadIdx.x / LPN;
    int sub = threadIdx.x % LPN;
    int q = sub % FH;
    int e = sub / FH;
    if (node >= N) return;
    float a0[8], a1[8], a2[8], a3[8];
#pragma unroll
    for (int i = 0; i < 8; ++i) { a0[i] = 0.f; a1[i] = 0.f; a2[i] = 0.f; a3[i] = 0.f; }
    if (e == 0) {
        float di = dinv[node];
        acc8(a0, tab[(size_t)node * FH + q], di * di);   // self-loop
    }
    int beg = row_ptr[node];
    int end = row_ptr[node + 1];
    int half = (end - beg) >> 1;
    int j = beg + e * half;
    int je = e ? end : (beg + half);
    for (; j + 3 < je; j += 4) {
        int2 p0 = ldnt2(perm + j);
        int2 p1 = ldnt2(perm + j + 1);
        int2 p2 = ldnt2(perm + j + 2);
        int2 p3 = ldnt2(perm + j + 3);
        int4 v0 = tab[(size_t)p0.x * FH + q];
        int4 v1 = tab[(size_t)p1.x * FH + q];
        int4 v2 = tab[(size_t)p2.x * FH + q];
        int4 v3 = tab[(size_t)p3.x * FH + q];
        acc8(a0, v0, __int_as_float(p0.y));
        acc8(a1, v1, __int_as_float(p1.y));
        acc8(a2, v2, __int_as_float(p2.y));
        acc8(a3, v3, __int_as_float(p3.y));
    }
    for (; j < je; ++j) {
        int2 p0 = ldnt2(perm + j);
        acc8(a0, tab[(size_t)p0.x * FH + q], __int_as_float(p0.y));
    }
    float r[8];
#pragma unroll
    for (int i = 0; i < 8; ++i) {
        r[i] = (a0[i] + a1[i]) + (a2[i] + a3[i]);
        r[i] += __shfl_xor(r[i], FH);     // merge edge halves
    }
    if (e) return;
    if (HALF_OUT) {
#pragma unroll
        for (int i = 0; i < 8; ++i) {
            float v = r[i] + bias[q * 8 + i];
            r[i] = v > 0.f ? v : expm1f(v);
        }
        ((int4*)outv)[(size_t)node * FH + q] = pack8h(r);
    } else {
        float4* o4 = (float4*)outv;
        float4 lo = {r[0], r[1], r[2], r[3]};
        float4 hi = {r[4], r[5], r[6], r[7]};
        size_t base = ((size_t)node * FH + q) * 2;
        o4[base] = lo;
        o4[base + 1] = hi;
    }
}

extern "C" void kernel_launch(void* const* d_in, const int* in_sizes, int n_in,
                              void* d_out, int out_size, void* d_ws, size_t ws_size,
                              hipStream_t stream) {
    const float* x  = (const float*)d_in[0];
    const int*   ei = (const int*)d_in[1];
    const float* w  = (const float*)d_in[2];
    const float* W0 = (const float*)d_in[3];
    const float* b0 = (const float*)d_in[4];
    const float* W1 = (const float*)d_in[5];
    const float* b1 = (const float*)d_in[6];
    const float* W2 = (const float*)d_in[7];
    const float* b2 = (const float*)d_in[8];
    const float* Wm = (const float*)d_in[9];
    const float* bm = (const float*)d_in[10];
    float* out = (float*)d_out;

    const int N = in_sizes[0] / 256;
    const int E = in_sizes[2];
    const int* src = ei;
    const int* dst = ei + E;
    const int nbuck = (N + 255) >> 8;

    char* ws = (char*)d_ws;
    size_t off = 0;
    auto alloc = [&](size_t bytes) {
        void* p = ws + off;
        off = (off + bytes + 255) & ~(size_t)255;
        return p;
    };
    float* dinv    = (float*)alloc((size_t)N * 4);
    int*   row_ptr = (int*)alloc(((size_t)N + 1) * 4);
    int*   bcnt    = (int*)alloc(520 * 4);
    int*   boff    = (int*)alloc(520 * 4);
    int*   gcur    = (int*)alloc(520 * 4);
    // bedge region (E*8 bytes), aliased by feature buffers after CSR build:
    char*  regE    = (char*)alloc((size_t)E * 8);
    int2*  perm    = (int2*)alloc((size_t)E * 8);

    int2*  bedge = (int2*)regE;
    size_t eo = 0;
    auto sub = [&](size_t bytes) {
        char* p = regE + eo;
        eo = (eo + bytes + 255) & ~(size_t)255;
        return p;
    };
    __half* XW_h  = (__half*)sub((size_t)N * 16 * 2);   // 3.2MB
    __half* H1_h  = (__half*)sub((size_t)N * 16 * 2);   // 3.2MB
    __half* H2_h  = (__half*)sub((size_t)N * 32 * 2);   // 6.4MB row-major [N][32]
    float*  AG1_f = (float*)sub((size_t)N * 16 * 4);    // 6.4MB
    float*  AG2_f = (float*)sub((size_t)N * 32 * 4);    // 12.8MB
    float*  H3_f  = (float*)sub((size_t)N * 32 * 4);    // 12.8MB (total ~44.8MB <= E*8)

    hipMemsetAsync(bcnt, 0, 520 * 4, stream);

    const int CH = 8192;
    const int sblk = (E + CH - 1) / CH;

    // ---- build CSR (layer-invariant, round-5 structure)
    bucket_hist<<<sblk, 256, 0, stream>>>(dst, bcnt, E, nbuck, CH);
    bucket_scan<<<1, 512, 0, stream>>>(bcnt, boff, gcur, nbuck);
    bucket_scatter<<<(E + 4095) / 4096, 256, 0, stream>>>(src, dst, w, gcur, bedge, E);
    sort_deg<<<nbuck, 256, 0, stream>>>(boff, bedge, row_ptr, dinv, N, E);
    sort_scatter<<<nbuck, 256, 0, stream>>>(boff, bedge, row_ptr, dinv, perm, N);
    // bedge dead from here; regE reused for feature buffers.

    const int AGB2 = (N + 63) / 64;     // FH=2: 4 lanes/node, 64 nodes/block
    const int AGB4 = (N + 31) / 32;     // FH=4: 8 lanes/node, 32 nodes/block

    // ---- layer 0: XW = x@W0 (fp16) ; h1 = elu(A.XW + b0) (fp16)
    gemm_x16<<<(N + 15) / 16, 256, 0, stream>>>(x, W0, XW_h, N);
    agg_es<2, true><<<AGB2, 256, 0, stream>>>(row_ptr, perm, (const int4*)XW_h, dinv, b0, H1_h, N);

    // ---- layer 1: AG1 = A.h1 (fp32) ; h2 = elu(AG1@W1 + b1) (fp16 [N][32])
    agg_es<2, false><<<AGB2, 256, 0, stream>>>(row_ptr, perm, (const int4*)H1_h, dinv, nullptr, AG1_f, N);
    gemm_small<16, 32, true, true><<<(N + 7) / 8, 256, 0, stream>>>(AG1_f, W1, b1, H2_h, N);

    // ---- layer 2: AG2 = A.h2 (single pass, fp16 [N][32] table)
    agg_es<4, false><<<AGB4, 256, 0, stream>>>(row_ptr, perm, (const int4*)H2_h, dinv, nullptr, AG2_f, N);
    gemm_small<32, 32, true, false><<<(N + 7) / 8, 256, 0, stream>>>(AG2_f, W2, b2, H3_f, N);

    // ---- head: out = h3@Wm + bm
    gemm_small<32, 16, false, false><<<(N + 15) / 16, 256, 0, stream>>>(H3_f, Wm, bm, out, N);
}

// Round 14
// 579.344 us; speedup vs baseline: 1.7412x; 1.0493x over previous
//
#include <hip/hip_runtime.h>
#include <hip/hip_fp16.h>
#include <cstdint>

// ---------------------------------------------------------------------------
// GCN: 3x GCNConv(+ELU) + linear head.
// Norm factorized: norm = dinv[s]*w*dinv[d]. Gather tables store
// t[n] = dinv[n]*f[n] (fp16); agg computes out = dinv[d]*(t[d] + sum w*t[s]).
// -> perm = (src, w); build needs NO dinv[src] gather and NO norm pass:
//    hist -> scan -> LDS-tile scatter -> bucket_sort (fused deg+dinv+scatter,
//    two sweeps of an L2-hot bucket run).
// Aggregation (round-13 proven, ~1 gather line/edge, 3 sweeps minimum):
//   L0: t0 = dinv*x@W0 fp16 [N][16] -> agg_es<2> -> t1 = dinv*h1 fp16
//   L1: t1 -> agg_es<2> -> AG1 fp32 ; gemm -> t2 = dinv*h2 fp16 [N][32]
//   L2: t2 -> agg_es<4> -> AG2 fp32 ; gemm -> H3 fp32 ; head gemm -> out
// ---------------------------------------------------------------------------

typedef float __attribute__((ext_vector_type(4))) f4v;

__device__ inline int2 ldnt2(const int2* p) {
    long long v = __builtin_nontemporal_load((const long long*)p);
    int2 r;
    r.x = (int)(unsigned)(v & 0xFFFFFFFFLL);
    r.y = (int)(unsigned)((unsigned long long)v >> 32);
    return r;
}
__device__ inline float4 ldnt4(const float4* p) {
    f4v v = __builtin_nontemporal_load((const f4v*)p);
    float4 r;
    r.x = v.x; r.y = v.y; r.z = v.z; r.w = v.w;
    return r;
}

union H2I { __half2 h; int i; };
__device__ inline int h2i(__half2 h) { H2I u; u.h = h; return u.i; }

__device__ inline void acc8(float* a, int4 v, float n) {
    H2I u0, u1, u2, u3;
    u0.i = v.x; u1.i = v.y; u2.i = v.z; u3.i = v.w;
    float2 f0 = __half22float2(u0.h);
    float2 f1 = __half22float2(u1.h);
    float2 f2 = __half22float2(u2.h);
    float2 f3 = __half22float2(u3.h);
    a[0] = fmaf(n, f0.x, a[0]); a[1] = fmaf(n, f0.y, a[1]);
    a[2] = fmaf(n, f1.x, a[2]); a[3] = fmaf(n, f1.y, a[3]);
    a[4] = fmaf(n, f2.x, a[4]); a[5] = fmaf(n, f2.y, a[5]);
    a[6] = fmaf(n, f3.x, a[6]); a[7] = fmaf(n, f3.y, a[7]);
}

__device__ inline int4 pack8h(const float* a) {
    int4 r;
    r.x = h2i(__floats2half2_rn(a[0], a[1]));
    r.y = h2i(__floats2half2_rn(a[2], a[3]));
    r.z = h2i(__floats2half2_rn(a[4], a[5]));
    r.w = h2i(__floats2half2_rn(a[6], a[7]));
    return r;
}

// ---- Pass A: per-bucket edge counts. bucket = dst >> 8.
__global__ void __launch_bounds__(256) bucket_hist(const int* __restrict__ dst,
                                                   int* __restrict__ bcnt,
                                                   int E, int nbuck, int chunk) {
    __shared__ int h[512];
    for (int i = threadIdx.x; i < 512; i += 256) h[i] = 0;
    __syncthreads();
    int c0 = blockIdx.x * chunk;
    int c1 = min(E, c0 + chunk);
    for (int i = c0 + threadIdx.x; i < c1; i += 256)
        atomicAdd(&h[((unsigned)dst[i]) >> 8], 1);
    __syncthreads();
    for (int i = threadIdx.x; i < nbuck; i += 256)
        if (h[i]) atomicAdd(&bcnt[i], h[i]);
}

// ---- scan of bucket counts -> boff[nbuck+1], global cursors.
__global__ void __launch_bounds__(512) bucket_scan(const int* __restrict__ bcnt,
                                                   int* __restrict__ boff,
                                                   int* __restrict__ gcur,
                                                   int nbuck) {
    __shared__ int part[512];
    int t = threadIdx.x;
    part[t] = (t < nbuck) ? bcnt[t] : 0;
    __syncthreads();
    for (int off = 1; off < 512; off <<= 1) {
        int v = part[t];
        int a = (t >= off) ? part[t - off] : 0;
        __syncthreads();
        part[t] = v + a;
        __syncthreads();
    }
    if (t < nbuck) {
        int excl = (t > 0) ? part[t - 1] : 0;
        boff[t] = excl;
        gcur[t] = excl;
        if (t == nbuck - 1) boff[nbuck] = part[t];  // == E
    }
}

// ---- Pass C: LDS-reorder scatter. TILE=4096 edges/block.
// pack: (local_dst(8b) << 24) | src(24b), payload = w
__global__ void __launch_bounds__(256) bucket_scatter(const int* __restrict__ src,
                                                      const int* __restrict__ dst,
                                                      const float* __restrict__ w,
                                                      int* __restrict__ gcur,
                                                      int2* __restrict__ bedge,
                                                      int E) {
    constexpr int TILE = 4096;
    __shared__ int h[512];
    __shared__ int lcnt[512];
    __shared__ int lofs[512];
    __shared__ int gb[512];
    __shared__ int part[256];
    __shared__ int2 sedge[TILE];
    __shared__ unsigned short sbuck[TILE];

    int t = threadIdx.x;
    int c0 = blockIdx.x * TILE;
    int mtile = min(TILE, E - c0);

    for (int i = t; i < 512; i += 256) { h[i] = 0; lcnt[i] = 0; }
    __syncthreads();

    int  my_dst[16];
    int  my_src[16];
    float my_w[16];
#pragma unroll
    for (int k = 0; k < 4; ++k) {
        int e0 = c0 + (t + k * 256) * 4;
        if (e0 + 4 <= E) {
            int4 d4 = *(const int4*)(dst + e0);
            int4 s4 = *(const int4*)(src + e0);
            float4 w4 = *(const float4*)(w + e0);
            my_dst[k*4+0]=d4.x; my_dst[k*4+1]=d4.y; my_dst[k*4+2]=d4.z; my_dst[k*4+3]=d4.w;
            my_src[k*4+0]=s4.x; my_src[k*4+1]=s4.y; my_src[k*4+2]=s4.z; my_src[k*4+3]=s4.w;
            my_w[k*4+0]=w4.x;  my_w[k*4+1]=w4.y;  my_w[k*4+2]=w4.z;  my_w[k*4+3]=w4.w;
        } else {
#pragma unroll
            for (int j = 0; j < 4; ++j) {
                int e = e0 + j;
                bool ok = e < E;
                my_dst[k*4+j] = ok ? dst[e] : -1;
                my_src[k*4+j] = ok ? src[e] : 0;
                my_w[k*4+j]   = ok ? w[e] : 0.f;
            }
        }
    }
#pragma unroll
    for (int j = 0; j < 16; ++j)
        if (my_dst[j] >= 0) atomicAdd(&h[((unsigned)my_dst[j]) >> 8], 1);
    __syncthreads();

    int a0 = h[2 * t], a1 = h[2 * t + 1];
    int s = a0 + a1;
    part[t] = s;
    __syncthreads();
    for (int off = 1; off < 256; off <<= 1) {
        int v = part[t];
        int a = (t >= off) ? part[t - off] : 0;
        __syncthreads();
        part[t] = v + a;
        __syncthreads();
    }
    int excl = part[t] - s;
    lofs[2 * t] = excl;
    lofs[2 * t + 1] = excl + a0;
    if (a0) gb[2 * t] = atomicAdd(&gcur[2 * t], a0) - excl;
    if (a1) gb[2 * t + 1] = atomicAdd(&gcur[2 * t + 1], a1) - (excl + a0);
    __syncthreads();

#pragma unroll
    for (int j = 0; j < 16; ++j) {
        int d = my_dst[j];
        if (d < 0) continue;
        unsigned ud = (unsigned)d;
        int b = ud >> 8;
        int p = lofs[b] + atomicAdd(&lcnt[b], 1);
        int2 e;
        e.x = (int)(((ud & 255u) << 24) | (unsigned)my_src[j]);
        e.y = __float_as_int(my_w[j]);
        sedge[p] = e;
        sbuck[p] = (unsigned short)b;
    }
    __syncthreads();

    for (int i = t; i < mtile; i += 256) {
        int b = sbuck[i];
        bedge[gb[b] + i] = sedge[i];
    }
}

// ---- Pass D (fused): per-bucket deg -> row_ptr,dinv ; scatter -> perm=(src,w).
// Two sweeps; the second re-reads the same ~130KB bucket run L2-hot.
__global__ void __launch_bounds__(256) bucket_sort(const int* __restrict__ boff,
                                                   const int2* __restrict__ bedge,
                                                   int* __restrict__ row_ptr,
                                                   float* __restrict__ dinv,
                                                   int2* __restrict__ perm,
                                                   int N, int E) {
    __shared__ int cnt[256];
    __shared__ float deg[256];
    __shared__ int part[256];
    __shared__ int cur[256];
    int b = blockIdx.x;
    int base = boff[b];
    int m = boff[b + 1] - base;
    int t = threadIdx.x;
    cnt[t] = 0;
    deg[t] = 0.f;
    __syncthreads();
    for (int i = t; i < m; i += 256) {
        int2 e = bedge[base + i];
        unsigned l = ((unsigned)e.x) >> 24;
        atomicAdd(&cnt[l], 1);
        atomicAdd(&deg[l], __int_as_float(e.y));
    }
    __syncthreads();
    part[t] = cnt[t];
    __syncthreads();
    for (int off = 1; off < 256; off <<= 1) {
        int v = part[t];
        int a = (t >= off) ? part[t - off] : 0;
        __syncthreads();
        part[t] = v + a;
        __syncthreads();
    }
    int excl = part[t] - cnt[t];
    cur[t] = excl;
    int node = b * 256 + t;
    if (node < N) {
        row_ptr[node] = base + excl;
        dinv[node] = rsqrtf(deg[t] + 1.0f);
    }
    if (b == 0 && t == 0) row_ptr[N] = E;
    __syncthreads();
    for (int i = t; i < m; i += 256) {
        int2 e = bedge[base + i];
        unsigned ux = (unsigned)e.x;
        unsigned l = ux >> 24;
        int pos = base + atomicAdd(&cur[l], 1);
        perm[pos] = make_int2((int)(ux & 0xFFFFFFu), e.y);   // (src, w)
    }
}

// x[N,256] @ W[256,16], prescaled by dinv[r] -> fp16 [N,16].
__global__ void __launch_bounds__(256) gemm_x16(const float* __restrict__ x,
                                                const float* __restrict__ W,
                                                const float* __restrict__ dinv,
                                                __half* __restrict__ xwh, int N) {
    __shared__ float Ws[256 * 16];
    for (int i = threadIdx.x; i < 256 * 16; i += 256) Ws[i] = W[i];
    __syncthreads();
    int c = threadIdx.x & 15;
    int rl = threadIdx.x >> 4;
    int r = blockIdx.x * 16 + rl;
    if (r >= N) return;
    const float4* x4 = (const float4*)(x + (size_t)r * 256);
    float acc = 0.f;
#pragma unroll 8
    for (int k4 = 0; k4 < 64; ++k4) {
        float4 v = ldnt4(x4 + k4);
        const float* wr = &Ws[k4 * 64 + c];
        acc += v.x * wr[0] + v.y * wr[16] + v.z * wr[32] + v.w * wr[48];
    }
    xwh[(size_t)r * 16 + c] = __float2half_rn(acc * dinv[r]);
}

// in[N,K] @ W[K,F] + bias -> out[N,F]. OUT_ELU: apply ELU.
// HALF_ROW: write fp16 row-major [N][F] prescaled by dinv[r]; else fp32.
template <int K, int F, bool OUT_ELU, bool HALF_ROW>
__global__ void __launch_bounds__(256) gemm_small(const float* __restrict__ in,
                                                  const float* __restrict__ W,
                                                  const float* __restrict__ bias,
                                                  const float* __restrict__ dinv,
                                                  void* __restrict__ outv, int N) {
    constexpr int ROWS = 256 / F;
    __shared__ float Ws[K * F];
    __shared__ float Is[ROWS * K];
    for (int i = threadIdx.x; i < K * F; i += 256) Ws[i] = W[i];
    int r0 = blockIdx.x * ROWS;
    for (int i = threadIdx.x; i < ROWS * K; i += 256)
        Is[i] = in[(size_t)r0 * K + i];
    __syncthreads();
    int c = threadIdx.x % F;
    int rl = threadIdx.x / F;
    int r = r0 + rl;
    float acc = bias[c];
#pragma unroll
    for (int k = 0; k < K; ++k) acc += Is[rl * K + k] * Ws[k * F + c];
    if (OUT_ELU) acc = acc > 0.f ? acc : expm1f(acc);
    if (HALF_ROW) {
        ((__half*)outv)[(size_t)r * F + c] = __float2half_rn(acc * dinv[r]);
    } else {
        ((float*)outv)[(size_t)r * F + c] = acc;
    }
}

// ---- fp16 prescaled-table gather-aggregate with edge-split lanes.
// Table: t[n] = dinv[n]*f[n], fp16 row-major [N][8*FH] (int4 = node*FH + q).
// Lanes/node = FH*2: q = feature chunk, e = edge half; shfl_xor(FH) merges.
// Math: sum = t[node] + sum_e w_e * t[src_e]; out = dinv[node]*sum [+b, ELU].
// HALF_OUT: store dinv[node]*elu(...) fp16 (next layer's table). Else fp32.
template <int FH, bool HALF_OUT>
__global__ void __launch_bounds__(256) agg_es(const int* __restrict__ row_ptr,
                                              const int2* __restrict__ perm,
                                              const int4* __restrict__ tab,
                                              const float* __restrict__ dinv,
                                              const float* __restrict__ bias,
                                              void* __restrict__ outv, int N) {
    constexpr int LPN = FH * 2;
    constexpr int NPB = 256 / LPN;
    int node = blockIdx.x * NPB + threadIdx.x / LPN;
    int sub = threadIdx.x % LPN;
    int q = sub % FH;
    int e = sub / FH;
    if (node >= N) return;
    float a0[8], a1[8], a2[8], a3[8];
#pragma unroll
    for (int i = 0; i < 8; ++i) { a0[i] = 0.f; a1[i] = 0.f; a2[i] = 0.f; a3[i] = 0.f; }
    if (e == 0) acc8(a0, tab[(size_t)node * FH + q], 1.0f);   // self-loop (w=1)
    int beg = row_ptr[node];
    int end = row_ptr[node + 1];
    int half = (end - beg) >> 1;
    int j = beg + e * half;
    int je = e ? end : (beg + half);
    for (; j + 3 < je; j += 4) {
        int2 p0 = ldnt2(perm + j);
        int2 p1 = ldnt2(perm + j + 1);
        int2 p2 = ldnt2(perm + j + 2);
        int2 p3 = ldnt2(perm + j + 3);
        int4 v0 = tab[(size_t)p0.x * FH + q];
        int4 v1 = tab[(size_t)p1.x * FH + q];
        int4 v2 = tab[(size_t)p2.x * FH + q];
        int4 v3 = tab[(size_t)p3.x * FH + q];
        acc8(a0, v0, __int_as_float(p0.y));
        acc8(a1, v1, __int_as_float(p1.y));
        acc8(a2, v2, __int_as_float(p2.y));
        acc8(a3, v3, __int_as_float(p3.y));
    }
    for (; j < je; ++j) {
        int2 p0 = ldnt2(perm + j);
        acc8(a0, tab[(size_t)p0.x * FH + q], __int_as_float(p0.y));
    }
    float r[8];
#pragma unroll
    for (int i = 0; i < 8; ++i) {
        r[i] = (a0[i] + a1[i]) + (a2[i] + a3[i]);
        r[i] += __shfl_xor(r[i], FH);     // merge edge halves
    }
    if (e) return;
    float dv = dinv[node];
    if (HALF_OUT) {
#pragma unroll
        for (int i = 0; i < 8; ++i) {
            float v = r[i] * dv + bias[q * 8 + i];
            v = v > 0.f ? v : expm1f(v);
            r[i] = v * dv;                 // prescale next table
        }
        ((int4*)outv)[(size_t)node * FH + q] = pack8h(r);
    } else {
        float4* o4 = (float4*)outv;
        float4 lo = {r[0] * dv, r[1] * dv, r[2] * dv, r[3] * dv};
        float4 hi = {r[4] * dv, r[5] * dv, r[6] * dv, r[7] * dv};
        size_t base = ((size_t)node * FH + q) * 2;
        o4[base] = lo;
        o4[base + 1] = hi;
    }
}

extern "C" void kernel_launch(void* const* d_in, const int* in_sizes, int n_in,
                              void* d_out, int out_size, void* d_ws, size_t ws_size,
                              hipStream_t stream) {
    const float* x  = (const float*)d_in[0];
    const int*   ei = (const int*)d_in[1];
    const float* w  = (const float*)d_in[2];
    const float* W0 = (const float*)d_in[3];
    const float* b0 = (const float*)d_in[4];
    const float* W1 = (const float*)d_in[5];
    const float* b1 = (const float*)d_in[6];
    const float* W2 = (const float*)d_in[7];
    const float* b2 = (const float*)d_in[8];
    const float* Wm = (const float*)d_in[9];
    const float* bm = (const float*)d_in[10];
    float* out = (float*)d_out;

    const int N = in_sizes[0] / 256;
    const int E = in_sizes[2];
    const int* src = ei;
    const int* dst = ei + E;
    const int nbuck = (N + 255) >> 8;

    char* ws = (char*)d_ws;
    size_t off = 0;
    auto alloc = [&](size_t bytes) {
        void* p = ws + off;
        off = (off + bytes + 255) & ~(size_t)255;
        return p;
    };
    float* dinv    = (float*)alloc((size_t)N * 4);
    int*   row_ptr = (int*)alloc(((size_t)N + 1) * 4);
    int*   bcnt    = (int*)alloc(520 * 4);
    int*   boff    = (int*)alloc(520 * 4);
    int*   gcur    = (int*)alloc(520 * 4);
    // bedge region (E*8 bytes), aliased by feature buffers after CSR build:
    char*  regE    = (char*)alloc((size_t)E * 8);
    int2*  perm    = (int2*)alloc((size_t)E * 8);

    int2*  bedge = (int2*)regE;
    size_t eo = 0;
    auto sub = [&](size_t bytes) {
        char* p = regE + eo;
        eo = (eo + bytes + 255) & ~(size_t)255;
        return p;
    };
    __half* T0_h  = (__half*)sub((size_t)N * 16 * 2);   // 3.2MB  dinv*xw
    __half* T1_h  = (__half*)sub((size_t)N * 16 * 2);   // 3.2MB  dinv*h1
    __half* T2_h  = (__half*)sub((size_t)N * 32 * 2);   // 6.4MB  dinv*h2 [N][32]
    float*  AG1_f = (float*)sub((size_t)N * 16 * 4);    // 6.4MB
    float*  AG2_f = (float*)sub((size_t)N * 32 * 4);    // 12.8MB
    float*  H3_f  = (float*)sub((size_t)N * 32 * 4);    // 12.8MB (total ~44.8MB <= E*8)

    hipMemsetAsync(bcnt, 0, 520 * 4, stream);

    const int CH = 8192;
    const int sblk = (E + CH - 1) / CH;

    // ---- build CSR (layer-invariant): perm = (src, w)
    bucket_hist<<<sblk, 256, 0, stream>>>(dst, bcnt, E, nbuck, CH);
    bucket_scan<<<1, 512, 0, stream>>>(bcnt, boff, gcur, nbuck);
    bucket_scatter<<<(E + 4095) / 4096, 256, 0, stream>>>(src, dst, w, gcur, bedge, E);
    bucket_sort<<<nbuck, 256, 0, stream>>>(boff, bedge, row_ptr, dinv, perm, N, E);
    // bedge dead from here; regE reused for feature buffers.

    const int AGB2 = (N + 63) / 64;     // FH=2: 4 lanes/node
    const int AGB4 = (N + 31) / 32;     // FH=4: 8 lanes/node

    // ---- layer 0: T0 = dinv*(x@W0) fp16 ; T1 = dinv*elu(dinv*sum + b0) fp16
    gemm_x16<<<(N + 15) / 16, 256, 0, stream>>>(x, W0, dinv, T0_h, N);
    agg_es<2, true><<<AGB2, 256, 0, stream>>>(row_ptr, perm, (const int4*)T0_h, dinv, b0, T1_h, N);

    // ---- layer 1: AG1 = dinv*sum(T1) fp32 ; T2 = dinv*elu(AG1@W1+b1) fp16
    agg_es<2, false><<<AGB2, 256, 0, stream>>>(row_ptr, perm, (const int4*)T1_h, dinv, nullptr, AG1_f, N);
    gemm_small<16, 32, true, true><<<(N + 7) / 8, 256, 0, stream>>>(AG1_f, W1, b1, dinv, T2_h, N);

    // ---- layer 2: AG2 = dinv*sum(T2) fp32 ; H3 = elu(AG2@W2+b2) fp32
    agg_es<4, false><<<AGB4, 256, 0, stream>>>(row_ptr, perm, (const int4*)T2_h, dinv, nullptr, AG2_f, N);
    gemm_small<32, 32, true, false><<<(N + 7) / 8, 256, 0, stream>>>(AG2_f, W2, b2, nullptr, H3_f, N);

    // ---- head: out = H3@Wm + bm
    gemm_small<32, 16, false, false><<<(N + 15) / 16, 256, 0, stream>>>(H3_f, Wm, bm, nullptr, out, N);
}

// Round 15
// 498.965 us; speedup vs baseline: 2.0216x; 1.1611x over previous
//
#include <hip/hip_runtime.h>
#include <hip/hip_fp16.h>
#include <cstdint>

// ---------------------------------------------------------------------------
// GCN: 3x GCNConv(+ELU) + linear head.
// Norm factorized: norm = dinv[s]*w*dinv[d]. Gather tables store
// t[n] = dinv[n]*f[n] (fp16); agg computes out = dinv[d]*(t[d] + sum w*t[s]).
// perm = (src, w); build: hist -> scan -> LDS-tile scatter -> bucket_sort.
// Round-15 change: perm reads in agg_es are PLAIN loads (round-6's
// nontemporal hint bypassed L2 -> HBM-latency floor on the edge stream);
// 8-deep gather unroll for more memory-level parallelism.
// ---------------------------------------------------------------------------

typedef float __attribute__((ext_vector_type(4))) f4v;

__device__ inline float4 ldnt4(const float4* p) {
    f4v v = __builtin_nontemporal_load((const f4v*)p);
    float4 r;
    r.x = v.x; r.y = v.y; r.z = v.z; r.w = v.w;
    return r;
}

union H2I { __half2 h; int i; };
__device__ inline int h2i(__half2 h) { H2I u; u.h = h; return u.i; }

__device__ inline void acc8(float* a, int4 v, float n) {
    H2I u0, u1, u2, u3;
    u0.i = v.x; u1.i = v.y; u2.i = v.z; u3.i = v.w;
    float2 f0 = __half22float2(u0.h);
    float2 f1 = __half22float2(u1.h);
    float2 f2 = __half22float2(u2.h);
    float2 f3 = __half22float2(u3.h);
    a[0] = fmaf(n, f0.x, a[0]); a[1] = fmaf(n, f0.y, a[1]);
    a[2] = fmaf(n, f1.x, a[2]); a[3] = fmaf(n, f1.y, a[3]);
    a[4] = fmaf(n, f2.x, a[4]); a[5] = fmaf(n, f2.y, a[5]);
    a[6] = fmaf(n, f3.x, a[6]); a[7] = fmaf(n, f3.y, a[7]);
}

__device__ inline int4 pack8h(const float* a) {
    int4 r;
    r.x = h2i(__floats2half2_rn(a[0], a[1]));
    r.y = h2i(__floats2half2_rn(a[2], a[3]));
    r.z = h2i(__floats2half2_rn(a[4], a[5]));
    r.w = h2i(__floats2half2_rn(a[6], a[7]));
    return r;
}

// ---- Pass A: per-bucket edge counts. bucket = dst >> 8.
__global__ void __launch_bounds__(256) bucket_hist(const int* __restrict__ dst,
                                                   int* __restrict__ bcnt,
                                                   int E, int nbuck, int chunk) {
    __shared__ int h[512];
    for (int i = threadIdx.x; i < 512; i += 256) h[i] = 0;
    __syncthreads();
    int c0 = blockIdx.x * chunk;
    int c1 = min(E, c0 + chunk);
    for (int i = c0 + threadIdx.x; i < c1; i += 256)
        atomicAdd(&h[((unsigned)dst[i]) >> 8], 1);
    __syncthreads();
    for (int i = threadIdx.x; i < nbuck; i += 256)
        if (h[i]) atomicAdd(&bcnt[i], h[i]);
}

// ---- scan of bucket counts -> boff[nbuck+1], global cursors.
__global__ void __launch_bounds__(512) bucket_scan(const int* __restrict__ bcnt,
                                                   int* __restrict__ boff,
                                                   int* __restrict__ gcur,
                                                   int nbuck) {
    __shared__ int part[512];
    int t = threadIdx.x;
    part[t] = (t < nbuck) ? bcnt[t] : 0;
    __syncthreads();
    for (int off = 1; off < 512; off <<= 1) {
        int v = part[t];
        int a = (t >= off) ? part[t - off] : 0;
        __syncthreads();
        part[t] = v + a;
        __syncthreads();
    }
    if (t < nbuck) {
        int excl = (t > 0) ? part[t - 1] : 0;
        boff[t] = excl;
        gcur[t] = excl;
        if (t == nbuck - 1) boff[nbuck] = part[t];  // == E
    }
}

// ---- Pass C: LDS-reorder scatter. TILE=4096 edges/block.
// pack: (local_dst(8b) << 24) | src(24b), payload = w
__global__ void __launch_bounds__(256) bucket_scatter(const int* __restrict__ src,
                                                      const int* __restrict__ dst,
                                                      const float* __restrict__ w,
                                                      int* __restrict__ gcur,
                                                      int2* __restrict__ bedge,
                                                      int E) {
    constexpr int TILE = 4096;
    __shared__ int h[512];
    __shared__ int lcnt[512];
    __shared__ int lofs[512];
    __shared__ int gb[512];
    __shared__ int part[256];
    __shared__ int2 sedge[TILE];
    __shared__ unsigned short sbuck[TILE];

    int t = threadIdx.x;
    int c0 = blockIdx.x * TILE;
    int mtile = min(TILE, E - c0);

    for (int i = t; i < 512; i += 256) { h[i] = 0; lcnt[i] = 0; }
    __syncthreads();

    int  my_dst[16];
    int  my_src[16];
    float my_w[16];
#pragma unroll
    for (int k = 0; k < 4; ++k) {
        int e0 = c0 + (t + k * 256) * 4;
        if (e0 + 4 <= E) {
            int4 d4 = *(const int4*)(dst + e0);
            int4 s4 = *(const int4*)(src + e0);
            float4 w4 = *(const float4*)(w + e0);
            my_dst[k*4+0]=d4.x; my_dst[k*4+1]=d4.y; my_dst[k*4+2]=d4.z; my_dst[k*4+3]=d4.w;
            my_src[k*4+0]=s4.x; my_src[k*4+1]=s4.y; my_src[k*4+2]=s4.z; my_src[k*4+3]=s4.w;
            my_w[k*4+0]=w4.x;  my_w[k*4+1]=w4.y;  my_w[k*4+2]=w4.z;  my_w[k*4+3]=w4.w;
        } else {
#pragma unroll
            for (int j = 0; j < 4; ++j) {
                int e = e0 + j;
                bool ok = e < E;
                my_dst[k*4+j] = ok ? dst[e] : -1;
                my_src[k*4+j] = ok ? src[e] : 0;
                my_w[k*4+j]   = ok ? w[e] : 0.f;
            }
        }
    }
#pragma unroll
    for (int j = 0; j < 16; ++j)
        if (my_dst[j] >= 0) atomicAdd(&h[((unsigned)my_dst[j]) >> 8], 1);
    __syncthreads();

    int a0 = h[2 * t], a1 = h[2 * t + 1];
    int s = a0 + a1;
    part[t] = s;
    __syncthreads();
    for (int off = 1; off < 256; off <<= 1) {
        int v = part[t];
        int a = (t >= off) ? part[t - off] : 0;
        __syncthreads();
        part[t] = v + a;
        __syncthreads();
    }
    int excl = part[t] - s;
    lofs[2 * t] = excl;
    lofs[2 * t + 1] = excl + a0;
    if (a0) gb[2 * t] = atomicAdd(&gcur[2 * t], a0) - excl;
    if (a1) gb[2 * t + 1] = atomicAdd(&gcur[2 * t + 1], a1) - (excl + a0);
    __syncthreads();

#pragma unroll
    for (int j = 0; j < 16; ++j) {
        int d = my_dst[j];
        if (d < 0) continue;
        unsigned ud = (unsigned)d;
        int b = ud >> 8;
        int p = lofs[b] + atomicAdd(&lcnt[b], 1);
        int2 e;
        e.x = (int)(((ud & 255u) << 24) | (unsigned)my_src[j]);
        e.y = __float_as_int(my_w[j]);
        sedge[p] = e;
        sbuck[p] = (unsigned short)b;
    }
    __syncthreads();

    for (int i = t; i < mtile; i += 256) {
        int b = sbuck[i];
        bedge[gb[b] + i] = sedge[i];
    }
}

// ---- Pass D (fused): per-bucket deg -> row_ptr,dinv ; scatter -> perm=(src,w).
__global__ void __launch_bounds__(256) bucket_sort(const int* __restrict__ boff,
                                                   const int2* __restrict__ bedge,
                                                   int* __restrict__ row_ptr,
                                                   float* __restrict__ dinv,
                                                   int2* __restrict__ perm,
                                                   int N, int E) {
    __shared__ int cnt[256];
    __shared__ float deg[256];
    __shared__ int part[256];
    __shared__ int cur[256];
    int b = blockIdx.x;
    int base = boff[b];
    int m = boff[b + 1] - base;
    int t = threadIdx.x;
    cnt[t] = 0;
    deg[t] = 0.f;
    __syncthreads();
    for (int i = t; i < m; i += 256) {
        int2 e = bedge[base + i];
        unsigned l = ((unsigned)e.x) >> 24;
        atomicAdd(&cnt[l], 1);
        atomicAdd(&deg[l], __int_as_float(e.y));
    }
    __syncthreads();
    part[t] = cnt[t];
    __syncthreads();
    for (int off = 1; off < 256; off <<= 1) {
        int v = part[t];
        int a = (t >= off) ? part[t - off] : 0;
        __syncthreads();
        part[t] = v + a;
        __syncthreads();
    }
    int excl = part[t] - cnt[t];
    cur[t] = excl;
    int node = b * 256 + t;
    if (node < N) {
        row_ptr[node] = base + excl;
        dinv[node] = rsqrtf(deg[t] + 1.0f);
    }
    if (b == 0 && t == 0) row_ptr[N] = E;
    __syncthreads();
    for (int i = t; i < m; i += 256) {
        int2 e = bedge[base + i];
        unsigned ux = (unsigned)e.x;
        unsigned l = ux >> 24;
        int pos = base + atomicAdd(&cur[l], 1);
        perm[pos] = make_int2((int)(ux & 0xFFFFFFu), e.y);   // (src, w)
    }
}

// x[N,256] @ W[256,16], prescaled by dinv[r] -> fp16 [N,16].
__global__ void __launch_bounds__(256) gemm_x16(const float* __restrict__ x,
                                                const float* __restrict__ W,
                                                const float* __restrict__ dinv,
                                                __half* __restrict__ xwh, int N) {
    __shared__ float Ws[256 * 16];
    for (int i = threadIdx.x; i < 256 * 16; i += 256) Ws[i] = W[i];
    __syncthreads();
    int c = threadIdx.x & 15;
    int rl = threadIdx.x >> 4;
    int r = blockIdx.x * 16 + rl;
    if (r >= N) return;
    const float4* x4 = (const float4*)(x + (size_t)r * 256);
    float acc = 0.f;
#pragma unroll 8
    for (int k4 = 0; k4 < 64; ++k4) {
        float4 v = ldnt4(x4 + k4);
        const float* wr = &Ws[k4 * 64 + c];
        acc += v.x * wr[0] + v.y * wr[16] + v.z * wr[32] + v.w * wr[48];
    }
    xwh[(size_t)r * 16 + c] = __float2half_rn(acc * dinv[r]);
}

// in[N,K] @ W[K,F] + bias -> out[N,F]. OUT_ELU: apply ELU.
// HALF_ROW: write fp16 row-major [N][F] prescaled by dinv[r]; else fp32.
template <int K, int F, bool OUT_ELU, bool HALF_ROW>
__global__ void __launch_bounds__(256) gemm_small(const float* __restrict__ in,
                                                  const float* __restrict__ W,
                                                  const float* __restrict__ bias,
                                                  const float* __restrict__ dinv,
                                                  void* __restrict__ outv, int N) {
    constexpr int ROWS = 256 / F;
    __shared__ float Ws[K * F];
    __shared__ float Is[ROWS * K];
    for (int i = threadIdx.x; i < K * F; i += 256) Ws[i] = W[i];
    int r0 = blockIdx.x * ROWS;
    for (int i = threadIdx.x; i < ROWS * K; i += 256)
        Is[i] = in[(size_t)r0 * K + i];
    __syncthreads();
    int c = threadIdx.x % F;
    int rl = threadIdx.x / F;
    int r = r0 + rl;
    float acc = bias[c];
#pragma unroll
    for (int k = 0; k < K; ++k) acc += Is[rl * K + k] * Ws[k * F + c];
    if (OUT_ELU) acc = acc > 0.f ? acc : expm1f(acc);
    if (HALF_ROW) {
        ((__half*)outv)[(size_t)r * F + c] = __float2half_rn(acc * dinv[r]);
    } else {
        ((float*)outv)[(size_t)r * F + c] = acc;
    }
}

// ---- fp16 prescaled-table gather-aggregate with edge-split lanes.
// Table: t[n] = dinv[n]*f[n], fp16 row-major [N][8*FH] (int4 = node*FH + q).
// Lanes/node = FH*2: q = feature chunk, e = edge half; shfl_xor(FH) merges.
// Math: sum = t[node] + sum_e w_e * t[src_e]; out = dinv[node]*sum [+b, ELU].
// PLAIN perm loads (L2-cached stream) + 8-deep gather unroll.
template <int FH, bool HALF_OUT>
__global__ void __launch_bounds__(256) agg_es(const int* __restrict__ row_ptr,
                                              const int2* __restrict__ perm,
                                              const int4* __restrict__ tab,
                                              const float* __restrict__ dinv,
                                              const float* __restrict__ bias,
                                              void* __restrict__ outv, int N) {
    constexpr int LPN = FH * 2;
    constexpr int NPB = 256 / LPN;
    int node = blockIdx.x * NPB + threadIdx.x / LPN;
    int sub = threadIdx.x % LPN;
    int q = sub % FH;
    int e = sub / FH;
    if (node >= N) return;
    float a0[8], a1[8], a2[8], a3[8];
#pragma unroll
    for (int i = 0; i < 8; ++i) { a0[i] = 0.f; a1[i] = 0.f; a2[i] = 0.f; a3[i] = 0.f; }
    if (e == 0) acc8(a0, tab[(size_t)node * FH + q], 1.0f);   // self-loop (w=1)
    int beg = row_ptr[node];
    int end = row_ptr[node + 1];
    int half = (end - beg) >> 1;
    int j = beg + e * half;
    int je = e ? end : (beg + half);
    for (; j + 7 < je; j += 8) {
        int2 p0 = perm[j];
        int2 p1 = perm[j + 1];
        int2 p2 = perm[j + 2];
        int2 p3 = perm[j + 3];
        int2 p4 = perm[j + 4];
        int2 p5 = perm[j + 5];
        int2 p6 = perm[j + 6];
        int2 p7 = perm[j + 7];
        int4 v0 = tab[(size_t)p0.x * FH + q];
        int4 v1 = tab[(size_t)p1.x * FH + q];
        int4 v2 = tab[(size_t)p2.x * FH + q];
        int4 v3 = tab[(size_t)p3.x * FH + q];
        int4 v4 = tab[(size_t)p4.x * FH + q];
        int4 v5 = tab[(size_t)p5.x * FH + q];
        int4 v6 = tab[(size_t)p6.x * FH + q];
        int4 v7 = tab[(size_t)p7.x * FH + q];
        acc8(a0, v0, __int_as_float(p0.y));
        acc8(a1, v1, __int_as_float(p1.y));
        acc8(a2, v2, __int_as_float(p2.y));
        acc8(a3, v3, __int_as_float(p3.y));
        acc8(a0, v4, __int_as_float(p4.y));
        acc8(a1, v5, __int_as_float(p5.y));
        acc8(a2, v6, __int_as_float(p6.y));
        acc8(a3, v7, __int_as_float(p7.y));
    }
    for (; j + 3 < je; j += 4) {
        int2 p0 = perm[j];
        int2 p1 = perm[j + 1];
        int2 p2 = perm[j + 2];
        int2 p3 = perm[j + 3];
        int4 v0 = tab[(size_t)p0.x * FH + q];
        int4 v1 = tab[(size_t)p1.x * FH + q];
        int4 v2 = tab[(size_t)p2.x * FH + q];
        int4 v3 = tab[(size_t)p3.x * FH + q];
        acc8(a0, v0, __int_as_float(p0.y));
        acc8(a1, v1, __int_as_float(p1.y));
        acc8(a2, v2, __int_as_float(p2.y));
        acc8(a3, v3, __int_as_float(p3.y));
    }
    for (; j < je; ++j) {
        int2 p0 = perm[j];
        acc8(a0, tab[(size_t)p0.x * FH + q], __int_as_float(p0.y));
    }
    float r[8];
#pragma unroll
    for (int i = 0; i < 8; ++i) {
        r[i] = (a0[i] + a1[i]) + (a2[i] + a3[i]);
        r[i] += __shfl_xor(r[i], FH);     // merge edge halves
    }
    if (e) return;
    float dv = dinv[node];
    if (HALF_OUT) {
#pragma unroll
        for (int i = 0; i < 8; ++i) {
            float v = r[i] * dv + bias[q * 8 + i];
            v = v > 0.f ? v : expm1f(v);
            r[i] = v * dv;                 // prescale next table
        }
        ((int4*)outv)[(size_t)node * FH + q] = pack8h(r);
    } else {
        float4* o4 = (float4*)outv;
        float4 lo = {r[0] * dv, r[1] * dv, r[2] * dv, r[3] * dv};
        float4 hi = {r[4] * dv, r[5] * dv, r[6] * dv, r[7] * dv};
        size_t base = ((size_t)node * FH + q) * 2;
        o4[base] = lo;
        o4[base + 1] = hi;
    }
}

extern "C" void kernel_launch(void* const* d_in, const int* in_sizes, int n_in,
                              void* d_out, int out_size, void* d_ws, size_t ws_size,
                              hipStream_t stream) {
    const float* x  = (const float*)d_in[0];
    const int*   ei = (const int*)d_in[1];
    const float* w  = (const float*)d_in[2];
    const float* W0 = (const float*)d_in[3];
    const float* b0 = (const float*)d_in[4];
    const float* W1 = (const float*)d_in[5];
    const float* b1 = (const float*)d_in[6];
    const float* W2 = (const float*)d_in[7];
    const float* b2 = (const float*)d_in[8];
    const float* Wm = (const float*)d_in[9];
    const float* bm = (const float*)d_in[10];
    float* out = (float*)d_out;

    const int N = in_sizes[0] / 256;
    const int E = in_sizes[2];
    const int* src = ei;
    const int* dst = ei + E;
    const int nbuck = (N + 255) >> 8;

    char* ws = (char*)d_ws;
    size_t off = 0;
    auto alloc = [&](size_t bytes) {
        void* p = ws + off;
        off = (off + bytes + 255) & ~(size_t)255;
        return p;
    };
    float* dinv    = (float*)alloc((size_t)N * 4);
    int*   row_ptr = (int*)alloc(((size_t)N + 1) * 4);
    int*   bcnt    = (int*)alloc(520 * 4);
    int*   boff    = (int*)alloc(520 * 4);
    int*   gcur    = (int*)alloc(520 * 4);
    // bedge region (E*8 bytes), aliased by feature buffers after CSR build:
    char*  regE    = (char*)alloc((size_t)E * 8);
    int2*  perm    = (int2*)alloc((size_t)E * 8);

    int2*  bedge = (int2*)regE;
    size_t eo = 0;
    auto sub = [&](size_t bytes) {
        char* p = regE + eo;
        eo = (eo + bytes + 255) & ~(size_t)255;
        return p;
    };
    __half* T0_h  = (__half*)sub((size_t)N * 16 * 2);   // 3.2MB  dinv*xw
    __half* T1_h  = (__half*)sub((size_t)N * 16 * 2);   // 3.2MB  dinv*h1
    __half* T2_h  = (__half*)sub((size_t)N * 32 * 2);   // 6.4MB  dinv*h2 [N][32]
    float*  AG1_f = (float*)sub((size_t)N * 16 * 4);    // 6.4MB
    float*  AG2_f = (float*)sub((size_t)N * 32 * 4);    // 12.8MB
    float*  H3_f  = (float*)sub((size_t)N * 32 * 4);    // 12.8MB (total ~44.8MB <= E*8)

    hipMemsetAsync(bcnt, 0, 520 * 4, stream);

    const int CH = 8192;
    const int sblk = (E + CH - 1) / CH;

    // ---- build CSR (layer-invariant): perm = (src, w)
    bucket_hist<<<sblk, 256, 0, stream>>>(dst, bcnt, E, nbuck, CH);
    bucket_scan<<<1, 512, 0, stream>>>(bcnt, boff, gcur, nbuck);
    bucket_scatter<<<(E + 4095) / 4096, 256, 0, stream>>>(src, dst, w, gcur, bedge, E);
    bucket_sort<<<nbuck, 256, 0, stream>>>(boff, bedge, row_ptr, dinv, perm, N, E);
    // bedge dead from here; regE reused for feature buffers.

    const int AGB2 = (N + 63) / 64;     // FH=2: 4 lanes/node
    const int AGB4 = (N + 31) / 32;     // FH=4: 8 lanes/node

    // ---- layer 0: T0 = dinv*(x@W0) fp16 ; T1 = dinv*elu(dinv*sum + b0) fp16
    gemm_x16<<<(N + 15) / 16, 256, 0, stream>>>(x, W0, dinv, T0_h, N);
    agg_es<2, true><<<AGB2, 256, 0, stream>>>(row_ptr, perm, (const int4*)T0_h, dinv, b0, T1_h, N);

    // ---- layer 1: AG1 = dinv*sum(T1) fp32 ; T2 = dinv*elu(AG1@W1+b1) fp16
    agg_es<2, false><<<AGB2, 256, 0, stream>>>(row_ptr, perm, (const int4*)T1_h, dinv, nullptr, AG1_f, N);
    gemm_small<16, 32, true, true><<<(N + 7) / 8, 256, 0, stream>>>(AG1_f, W1, b1, dinv, T2_h, N);

    // ---- layer 2: AG2 = dinv*sum(T2) fp32 ; H3 = elu(AG2@W2+b2) fp32
    agg_es<4, false><<<AGB4, 256, 0, stream>>>(row_ptr, perm, (const int4*)T2_h, dinv, nullptr, AG2_f, N);
    gemm_small<32, 32, true, false><<<(N + 7) / 8, 256, 0, stream>>>(AG2_f, W2, b2, nullptr, H3_f, N);

    // ---- head: out = H3@Wm + bm
    gemm_small<32, 16, false, false><<<(N + 15) / 16, 256, 0, stream>>>(H3_f, Wm, bm, nullptr, out, N);
}

// Round 16
// 467.050 us; speedup vs baseline: 2.1598x; 1.0683x over previous
//
#include <hip/hip_runtime.h>
#include <hip/hip_fp16.h>
#include <cstdint>

// ---------------------------------------------------------------------------
// GCN: 3x GCNConv(+ELU) + linear head.
// Norm factorized: norm = dinv[s]*w*dinv[d]. Gather tables store
// t[n] = dinv[n]*f[n] (fp16); agg computes out = dinv[d]*(t[d] + sum w*t[s]).
// perm = (src, w); build: hist -> scan -> LDS-tile scatter (512 thr) ->
// bucket_sort (1024 thr). Agg: plain-load perm stream + fp16 L2-resident
// tables + edge-split lanes (round-15 proven, 499us).
// Round-16 change: build-side occupancy only.
// ---------------------------------------------------------------------------

typedef float __attribute__((ext_vector_type(4))) f4v;

__device__ inline float4 ldnt4(const float4* p) {
    f4v v = __builtin_nontemporal_load((const f4v*)p);
    float4 r;
    r.x = v.x; r.y = v.y; r.z = v.z; r.w = v.w;
    return r;
}

union H2I { __half2 h; int i; };
__device__ inline int h2i(__half2 h) { H2I u; u.h = h; return u.i; }

__device__ inline void acc8(float* a, int4 v, float n) {
    H2I u0, u1, u2, u3;
    u0.i = v.x; u1.i = v.y; u2.i = v.z; u3.i = v.w;
    float2 f0 = __half22float2(u0.h);
    float2 f1 = __half22float2(u1.h);
    float2 f2 = __half22float2(u2.h);
    float2 f3 = __half22float2(u3.h);
    a[0] = fmaf(n, f0.x, a[0]); a[1] = fmaf(n, f0.y, a[1]);
    a[2] = fmaf(n, f1.x, a[2]); a[3] = fmaf(n, f1.y, a[3]);
    a[4] = fmaf(n, f2.x, a[4]); a[5] = fmaf(n, f2.y, a[5]);
    a[6] = fmaf(n, f3.x, a[6]); a[7] = fmaf(n, f3.y, a[7]);
}

__device__ inline int4 pack8h(const float* a) {
    int4 r;
    r.x = h2i(__floats2half2_rn(a[0], a[1]));
    r.y = h2i(__floats2half2_rn(a[2], a[3]));
    r.z = h2i(__floats2half2_rn(a[4], a[5]));
    r.w = h2i(__floats2half2_rn(a[6], a[7]));
    return r;
}

// ---- Pass A: per-bucket edge counts. bucket = dst >> 8.
__global__ void __launch_bounds__(256) bucket_hist(const int* __restrict__ dst,
                                                   int* __restrict__ bcnt,
                                                   int E, int nbuck, int chunk) {
    __shared__ int h[512];
    for (int i = threadIdx.x; i < 512; i += 256) h[i] = 0;
    __syncthreads();
    int c0 = blockIdx.x * chunk;
    int c1 = min(E, c0 + chunk);
    for (int i = c0 + threadIdx.x; i < c1; i += 256)
        atomicAdd(&h[((unsigned)dst[i]) >> 8], 1);
    __syncthreads();
    for (int i = threadIdx.x; i < nbuck; i += 256)
        if (h[i]) atomicAdd(&bcnt[i], h[i]);
}

// ---- scan of bucket counts -> boff[nbuck+1], global cursors.
__global__ void __launch_bounds__(512) bucket_scan(const int* __restrict__ bcnt,
                                                   int* __restrict__ boff,
                                                   int* __restrict__ gcur,
                                                   int nbuck) {
    __shared__ int part[512];
    int t = threadIdx.x;
    part[t] = (t < nbuck) ? bcnt[t] : 0;
    __syncthreads();
    for (int off = 1; off < 512; off <<= 1) {
        int v = part[t];
        int a = (t >= off) ? part[t - off] : 0;
        __syncthreads();
        part[t] = v + a;
        __syncthreads();
    }
    if (t < nbuck) {
        int excl = (t > 0) ? part[t - 1] : 0;
        boff[t] = excl;
        gcur[t] = excl;
        if (t == nbuck - 1) boff[nbuck] = part[t];  // == E
    }
}

// ---- Pass C: LDS counting-sort of 4096-edge tiles (512 thr, 8 edges/thr).
// pack: (local_dst(8b) << 24) | src(24b), payload = w
__global__ void __launch_bounds__(512) bucket_scatter(const int* __restrict__ src,
                                                      const int* __restrict__ dst,
                                                      const float* __restrict__ w,
                                                      int* __restrict__ gcur,
                                                      int2* __restrict__ bedge,
                                                      int E) {
    constexpr int TILE = 4096;
    __shared__ int hc[512];     // histogram, then cursor (local offsets)
    __shared__ int gb[512];
    __shared__ int part[512];
    __shared__ int2 sedge[TILE];
    __shared__ unsigned short sbuck[TILE];

    int t = threadIdx.x;
    int c0 = blockIdx.x * TILE;
    int mtile = min(TILE, E - c0);

    hc[t] = 0;
    __syncthreads();

    int  my_d[8];
    int  my_s[8];
    float my_w[8];
#pragma unroll
    for (int k = 0; k < 2; ++k) {
        int e0 = c0 + (t + k * 512) * 4;
        if (e0 + 4 <= E) {
            int4 d4 = *(const int4*)(dst + e0);
            int4 s4 = *(const int4*)(src + e0);
            float4 w4 = *(const float4*)(w + e0);
            my_d[k*4+0]=d4.x; my_d[k*4+1]=d4.y; my_d[k*4+2]=d4.z; my_d[k*4+3]=d4.w;
            my_s[k*4+0]=s4.x; my_s[k*4+1]=s4.y; my_s[k*4+2]=s4.z; my_s[k*4+3]=s4.w;
            my_w[k*4+0]=w4.x; my_w[k*4+1]=w4.y; my_w[k*4+2]=w4.z; my_w[k*4+3]=w4.w;
        } else {
#pragma unroll
            for (int j = 0; j < 4; ++j) {
                int e = e0 + j;
                bool ok = e < E;
                my_d[k*4+j] = ok ? dst[e] : -1;
                my_s[k*4+j] = ok ? src[e] : 0;
                my_w[k*4+j] = ok ? w[e] : 0.f;
            }
        }
    }
#pragma unroll
    for (int j = 0; j < 8; ++j)
        if (my_d[j] >= 0) atomicAdd(&hc[((unsigned)my_d[j]) >> 8], 1);
    __syncthreads();

    int hb = hc[t];
    part[t] = hb;
    __syncthreads();
    for (int off = 1; off < 512; off <<= 1) {
        int v = part[t];
        int a = (t >= off) ? part[t - off] : 0;
        __syncthreads();
        part[t] = v + a;
        __syncthreads();
    }
    int excl = part[t] - hb;
    hc[t] = excl;                                   // cursor = local offset
    gb[t] = hb ? (atomicAdd(&gcur[t], hb) - excl) : 0;
    __syncthreads();

#pragma unroll
    for (int j = 0; j < 8; ++j) {
        int d = my_d[j];
        if (d < 0) continue;
        unsigned ud = (unsigned)d;
        int b = ud >> 8;
        int p = atomicAdd(&hc[b], 1);
        sedge[p] = make_int2((int)(((ud & 255u) << 24) | (unsigned)my_s[j]),
                             __float_as_int(my_w[j]));
        sbuck[p] = (unsigned short)b;
    }
    __syncthreads();

    for (int i = t; i < mtile; i += 512) {
        int b = sbuck[i];
        bedge[gb[b] + i] = sedge[i];
    }
}

// ---- Pass D (fused, 1024 thr): per-bucket deg -> row_ptr,dinv ;
// scatter -> perm=(src,w). Second sweep re-reads the L2-hot bucket run.
__global__ void __launch_bounds__(1024) bucket_sort(const int* __restrict__ boff,
                                                    const int2* __restrict__ bedge,
                                                    int* __restrict__ row_ptr,
                                                    float* __restrict__ dinv,
                                                    int2* __restrict__ perm,
                                                    int N, int E) {
    __shared__ int cnt[256];
    __shared__ float deg[256];
    __shared__ int part[256];
    __shared__ int cur[256];
    int b = blockIdx.x;
    int base = boff[b];
    int m = boff[b + 1] - base;
    int t = threadIdx.x;
    if (t < 256) { cnt[t] = 0; deg[t] = 0.f; }
    __syncthreads();
    for (int i = t; i < m; i += 1024) {
        int2 e = bedge[base + i];
        unsigned l = ((unsigned)e.x) >> 24;
        atomicAdd(&cnt[l], 1);
        atomicAdd(&deg[l], __int_as_float(e.y));
    }
    __syncthreads();
    if (t < 256) part[t] = cnt[t];
    __syncthreads();
    for (int off = 1; off < 256; off <<= 1) {
        int v = 0, a = 0;
        if (t < 256) { v = part[t]; a = (t >= off) ? part[t - off] : 0; }
        __syncthreads();
        if (t < 256) part[t] = v + a;
        __syncthreads();
    }
    if (t < 256) {
        int excl = part[t] - cnt[t];
        cur[t] = excl;
        int node = b * 256 + t;
        if (node < N) {
            row_ptr[node] = base + excl;
            dinv[node] = rsqrtf(deg[t] + 1.0f);
        }
    }
    if (b == 0 && t == 0) row_ptr[N] = E;
    __syncthreads();
    for (int i = t; i < m; i += 1024) {
        int2 e = bedge[base + i];
        unsigned ux = (unsigned)e.x;
        unsigned l = ux >> 24;
        int pos = base + atomicAdd(&cur[l], 1);
        perm[pos] = make_int2((int)(ux & 0xFFFFFFu), e.y);   // (src, w)
    }
}

// x[N,256] @ W[256,16], prescaled by dinv[r] -> fp16 [N,16].
__global__ void __launch_bounds__(256) gemm_x16(const float* __restrict__ x,
                                                const float* __restrict__ W,
                                                const float* __restrict__ dinv,
                                                __half* __restrict__ xwh, int N) {
    __shared__ float Ws[256 * 16];
    for (int i = threadIdx.x; i < 256 * 16; i += 256) Ws[i] = W[i];
    __syncthreads();
    int c = threadIdx.x & 15;
    int rl = threadIdx.x >> 4;
    int r = blockIdx.x * 16 + rl;
    if (r >= N) return;
    const float4* x4 = (const float4*)(x + (size_t)r * 256);
    float acc = 0.f;
#pragma unroll 8
    for (int k4 = 0; k4 < 64; ++k4) {
        float4 v = ldnt4(x4 + k4);
        const float* wr = &Ws[k4 * 64 + c];
        acc += v.x * wr[0] + v.y * wr[16] + v.z * wr[32] + v.w * wr[48];
    }
    xwh[(size_t)r * 16 + c] = __float2half_rn(acc * dinv[r]);
}

// in[N,K] @ W[K,F] + bias -> out[N,F]. OUT_ELU: apply ELU.
// HALF_ROW: write fp16 row-major [N][F] prescaled by dinv[r]; else fp32.
template <int K, int F, bool OUT_ELU, bool HALF_ROW>
__global__ void __launch_bounds__(256) gemm_small(const float* __restrict__ in,
                                                  const float* __restrict__ W,
                                                  const float* __restrict__ bias,
                                                  const float* __restrict__ dinv,
                                                  void* __restrict__ outv, int N) {
    constexpr int ROWS = 256 / F;
    __shared__ float Ws[K * F];
    __shared__ float Is[ROWS * K];
    for (int i = threadIdx.x; i < K * F; i += 256) Ws[i] = W[i];
    int r0 = blockIdx.x * ROWS;
    for (int i = threadIdx.x; i < ROWS * K; i += 256)
        Is[i] = in[(size_t)r0 * K + i];
    __syncthreads();
    int c = threadIdx.x % F;
    int rl = threadIdx.x / F;
    int r = r0 + rl;
    float acc = bias[c];
#pragma unroll
    for (int k = 0; k < K; ++k) acc += Is[rl * K + k] * Ws[k * F + c];
    if (OUT_ELU) acc = acc > 0.f ? acc : expm1f(acc);
    if (HALF_ROW) {
        ((__half*)outv)[(size_t)r * F + c] = __float2half_rn(acc * dinv[r]);
    } else {
        ((float*)outv)[(size_t)r * F + c] = acc;
    }
}

// ---- fp16 prescaled-table gather-aggregate with edge-split lanes.
// Table: t[n] = dinv[n]*f[n], fp16 row-major [N][8*FH] (int4 = node*FH + q).
// Lanes/node = FH*2: q = feature chunk, e = edge half; shfl_xor(FH) merges.
// Math: sum = t[node] + sum_e w_e * t[src_e]; out = dinv[node]*sum [+b, ELU].
template <int FH, bool HALF_OUT>
__global__ void __launch_bounds__(256) agg_es(const int* __restrict__ row_ptr,
                                              const int2* __restrict__ perm,
                                              const int4* __restrict__ tab,
                                              const float* __restrict__ dinv,
                                              const float* __restrict__ bias,
                                              void* __restrict__ outv, int N) {
    constexpr int LPN = FH * 2;
    constexpr int NPB = 256 / LPN;
    int node = blockIdx.x * NPB + threadIdx.x / LPN;
    int sub = threadIdx.x % LPN;
    int q = sub % FH;
    int e = sub / FH;
    if (node >= N) return;
    float a0[8], a1[8], a2[8], a3[8];
#pragma unroll
    for (int i = 0; i < 8; ++i) { a0[i] = 0.f; a1[i] = 0.f; a2[i] = 0.f; a3[i] = 0.f; }
    if (e == 0) acc8(a0, tab[(size_t)node * FH + q], 1.0f);   // self-loop (w=1)
    int beg = row_ptr[node];
    int end = row_ptr[node + 1];
    int half = (end - beg) >> 1;
    int j = beg + e * half;
    int je = e ? end : (beg + half);
    for (; j + 7 < je; j += 8) {
        int2 p0 = perm[j];
        int2 p1 = perm[j + 1];
        int2 p2 = perm[j + 2];
        int2 p3 = perm[j + 3];
        int2 p4 = perm[j + 4];
        int2 p5 = perm[j + 5];
        int2 p6 = perm[j + 6];
        int2 p7 = perm[j + 7];
        int4 v0 = tab[(size_t)p0.x * FH + q];
        int4 v1 = tab[(size_t)p1.x * FH + q];
        int4 v2 = tab[(size_t)p2.x * FH + q];
        int4 v3 = tab[(size_t)p3.x * FH + q];
        int4 v4 = tab[(size_t)p4.x * FH + q];
        int4 v5 = tab[(size_t)p5.x * FH + q];
        int4 v6 = tab[(size_t)p6.x * FH + q];
        int4 v7 = tab[(size_t)p7.x * FH + q];
        acc8(a0, v0, __int_as_float(p0.y));
        acc8(a1, v1, __int_as_float(p1.y));
        acc8(a2, v2, __int_as_float(p2.y));
        acc8(a3, v3, __int_as_float(p3.y));
        acc8(a0, v4, __int_as_float(p4.y));
        acc8(a1, v5, __int_as_float(p5.y));
        acc8(a2, v6, __int_as_float(p6.y));
        acc8(a3, v7, __int_as_float(p7.y));
    }
    for (; j + 3 < je; j += 4) {
        int2 p0 = perm[j];
        int2 p1 = perm[j + 1];
        int2 p2 = perm[j + 2];
        int2 p3 = perm[j + 3];
        int4 v0 = tab[(size_t)p0.x * FH + q];
        int4 v1 = tab[(size_t)p1.x * FH + q];
        int4 v2 = tab[(size_t)p2.x * FH + q];
        int4 v3 = tab[(size_t)p3.x * FH + q];
        acc8(a0, v0, __int_as_float(p0.y));
        acc8(a1, v1, __int_as_float(p1.y));
        acc8(a2, v2, __int_as_float(p2.y));
        acc8(a3, v3, __int_as_float(p3.y));
    }
    for (; j < je; ++j) {
        int2 p0 = perm[j];
        acc8(a0, tab[(size_t)p0.x * FH + q], __int_as_float(p0.y));
    }
    float r[8];
#pragma unroll
    for (int i = 0; i < 8; ++i) {
        r[i] = (a0[i] + a1[i]) + (a2[i] + a3[i]);
        r[i] += __shfl_xor(r[i], FH);     // merge edge halves
    }
    if (e) return;
    float dv = dinv[node];
    if (HALF_OUT) {
#pragma unroll
        for (int i = 0; i < 8; ++i) {
            float v = r[i] * dv + bias[q * 8 + i];
            v = v > 0.f ? v : expm1f(v);
            r[i] = v * dv;                 // prescale next table
        }
        ((int4*)outv)[(size_t)node * FH + q] = pack8h(r);
    } else {
        float4* o4 = (float4*)outv;
        float4 lo = {r[0] * dv, r[1] * dv, r[2] * dv, r[3] * dv};
        float4 hi = {r[4] * dv, r[5] * dv, r[6] * dv, r[7] * dv};
        size_t base = ((size_t)node * FH + q) * 2;
        o4[base] = lo;
        o4[base + 1] = hi;
    }
}

extern "C" void kernel_launch(void* const* d_in, const int* in_sizes, int n_in,
                              void* d_out, int out_size, void* d_ws, size_t ws_size,
                              hipStream_t stream) {
    const float* x  = (const float*)d_in[0];
    const int*   ei = (const int*)d_in[1];
    const float* w  = (const float*)d_in[2];
    const float* W0 = (const float*)d_in[3];
    const float* b0 = (const float*)d_in[4];
    const float* W1 = (const float*)d_in[5];
    const float* b1 = (const float*)d_in[6];
    const float* W2 = (const float*)d_in[7];
    const float* b2 = (const float*)d_in[8];
    const float* Wm = (const float*)d_in[9];
    const float* bm = (const float*)d_in[10];
    float* out = (float*)d_out;

    const int N = in_sizes[0] / 256;
    const int E = in_sizes[2];
    const int* src = ei;
    const int* dst = ei + E;
    const int nbuck = (N + 255) >> 8;

    char* ws = (char*)d_ws;
    size_t off = 0;
    auto alloc = [&](size_t bytes) {
        void* p = ws + off;
        off = (off + bytes + 255) & ~(size_t)255;
        return p;
    };
    float* dinv    = (float*)alloc((size_t)N * 4);
    int*   row_ptr = (int*)alloc(((size_t)N + 1) * 4);
    int*   bcnt    = (int*)alloc(520 * 4);
    int*   boff    = (int*)alloc(520 * 4);
    int*   gcur    = (int*)alloc(520 * 4);
    // bedge region (E*8 bytes), aliased by feature buffers after CSR build:
    char*  regE    = (char*)alloc((size_t)E * 8);
    int2*  perm    = (int2*)alloc((size_t)E * 8);

    int2*  bedge = (int2*)regE;
    size_t eo = 0;
    auto sub = [&](size_t bytes) {
        char* p = regE + eo;
        eo = (eo + bytes + 255) & ~(size_t)255;
        return p;
    };
    __half* T0_h  = (__half*)sub((size_t)N * 16 * 2);   // 3.2MB  dinv*xw
    __half* T1_h  = (__half*)sub((size_t)N * 16 * 2);   // 3.2MB  dinv*h1
    __half* T2_h  = (__half*)sub((size_t)N * 32 * 2);   // 6.4MB  dinv*h2 [N][32]
    float*  AG1_f = (float*)sub((size_t)N * 16 * 4);    // 6.4MB
    float*  AG2_f = (float*)sub((size_t)N * 32 * 4);    // 12.8MB
    float*  H3_f  = (float*)sub((size_t)N * 32 * 4);    // 12.8MB (total ~44.8MB <= E*8)

    hipMemsetAsync(bcnt, 0, 520 * 4, stream);

    const int CH = 8192;
    const int sblk = (E + CH - 1) / CH;

    // ---- build CSR (layer-invariant): perm = (src, w)
    bucket_hist<<<sblk, 256, 0, stream>>>(dst, bcnt, E, nbuck, CH);
    bucket_scan<<<1, 512, 0, stream>>>(bcnt, boff, gcur, nbuck);
    bucket_scatter<<<(E + 4095) / 4096, 512, 0, stream>>>(src, dst, w, gcur, bedge, E);
    bucket_sort<<<nbuck, 1024, 0, stream>>>(boff, bedge, row_ptr, dinv, perm, N, E);
    // bedge dead from here; regE reused for feature buffers.

    const int AGB2 = (N + 63) / 64;     // FH=2: 4 lanes/node
    const int AGB4 = (N + 31) / 32;     // FH=4: 8 lanes/node

    // ---- layer 0: T0 = dinv*(x@W0) fp16 ; T1 = dinv*elu(dinv*sum + b0) fp16
    gemm_x16<<<(N + 15) / 16, 256, 0, stream>>>(x, W0, dinv, T0_h, N);
    agg_es<2, true><<<AGB2, 256, 0, stream>>>(row_ptr, perm, (const int4*)T0_h, dinv, b0, T1_h, N);

    // ---- layer 1: AG1 = dinv*sum(T1) fp32 ; T2 = dinv*elu(AG1@W1+b1) fp16
    agg_es<2, false><<<AGB2, 256, 0, stream>>>(row_ptr, perm, (const int4*)T1_h, dinv, nullptr, AG1_f, N);
    gemm_small<16, 32, true, true><<<(N + 7) / 8, 256, 0, stream>>>(AG1_f, W1, b1, dinv, T2_h, N);

    // ---- layer 2: AG2 = dinv*sum(T2) fp32 ; H3 = elu(AG2@W2+b2) fp32
    agg_es<4, false><<<AGB4, 256, 0, stream>>>(row_ptr, perm, (const int4*)T2_h, dinv, nullptr, AG2_f, N);
    gemm_small<32, 32, true, false><<<(N + 7) / 8, 256, 0, stream>>>(AG2_f, W2, b2, nullptr, H3_f, N);

    // ---- head: out = H3@Wm + bm
    gemm_small<32, 16, false, false><<<(N + 15) / 16, 256, 0, stream>>>(H3_f, Wm, bm, nullptr, out, N);
}